// Round 13
// baseline (378.695 us; speedup 1.0000x reference)
//
#include <hip/hip_runtime.h>
#include <hip/hip_bf16.h>
#include <math.h>

#define N_TOK 8192
#define D_DIM 512
#define F_DIM 256
#define E_NUM 64
#define SH_NUM 2
#define K_TOP 6
#define CAP   1536
#define M_ENT (N_TOK * K_TOP)   // 49152
#define NCHUNK (M_ENT / 256)    // 192

#define EW_STRIDE 393216            // shorts per expert blob (48 chunks x 8192)
#define E_TOT (E_NUM + SH_NUM)      // 66
#define X_BF_BYTES   (8388608ull)
#define WT_BYTES     ((size_t)E_TOT * EW_STRIDE * 2)
#define TOK_ROUTED   (E_NUM * CAP)                   // 98304
#define TOK_TOTAL    (TOK_ROUTED + SH_NUM * N_TOK)   // 114688 (legacy sizing)
#define EO_BYTES     ((size_t)TOK_ROUTED * D_DIM * 2) // routed rows only
#define RWT_BYTES    131072ull

typedef __attribute__((ext_vector_type(8))) short bf16x8;
typedef __attribute__((ext_vector_type(8))) short short8;
typedef __attribute__((ext_vector_type(4))) float f32x4;

__device__ __forceinline__ ushort f2bf(float f) {
  union { float f; unsigned u; } c; c.f = f;
  return (ushort)((c.u + 0x7FFFu + ((c.u >> 16) & 1u)) >> 16);
}
__device__ __forceinline__ float bf2f(ushort h) {
  union { unsigned u; float f; } c; c.u = ((unsigned)h) << 16;
  return c.f;
}

// ---------------- legacy router (small-ws path) ----------------
__global__ void router_topk(const float* __restrict__ x, const float* __restrict__ rw,
                            const float* __restrict__ bias, int* __restrict__ topk_i,
                            float* __restrict__ topk_p) {
  const int wave = threadIdx.x >> 6;
  const int lane = threadIdx.x & 63;
  const int n = blockIdx.x * 4 + wave;
  if (n >= N_TOK) return;

  const float4* xr = (const float4*)(x + (size_t)n * D_DIM);
  const float4* wr = (const float4*)(rw + (size_t)lane * D_DIM);
  float acc = 0.f;
  #pragma unroll 4
  for (int d4 = 0; d4 < D_DIM / 4; ++d4) {
    float4 xv = xr[d4]; float4 wv = wr[d4];
    acc += xv.x * wv.x + xv.y * wv.y + xv.z * wv.z + xv.w * wv.w;
  }
  float logit = acc + bias[lane];

  float m = logit;
  for (int off = 32; off > 0; off >>= 1) m = fmaxf(m, __shfl_xor(m, off));
  float p = expf(logit - m);
  float s = p;
  for (int off = 32; off > 0; off >>= 1) s += __shfl_xor(s, off);
  float prob = p / s;

  float myp = prob;
  float gsum = 0.f;
  float myg = 0.f; int myi = -1;
  for (int k = 0; k < K_TOP; ++k) {
    float bp = myp; int bi = lane;
    for (int off = 32; off > 0; off >>= 1) {
      float op = __shfl_xor(bp, off); int oi = __shfl_xor(bi, off);
      if (op > bp || (op == bp && oi < bi)) { bp = op; bi = oi; }
    }
    gsum += bp;
    if (lane == k) { myg = bp; myi = bi; }
    if (lane == bi) myp = -1.f;
  }
  if (lane < K_TOP) {
    topk_i[n * K_TOP + lane] = myi;
    topk_p[n * K_TOP + lane] = myg / (gsum + 1e-9f);
  }
}

__device__ __forceinline__ void softmax_topk_write(float logit, int n, int lane,
                                                   int* __restrict__ topk_i,
                                                   float* __restrict__ topk_p) {
  float m = logit;
  for (int off = 32; off > 0; off >>= 1) m = fmaxf(m, __shfl_xor(m, off));
  float p = expf(logit - m);
  float s = p;
  for (int off = 32; off > 0; off >>= 1) s += __shfl_xor(s, off);
  float prob = p / s;

  float myp = prob;
  float gsum = 0.f;
  float myg = 0.f; int myi = -1;
  #pragma unroll 1
  for (int k = 0; k < K_TOP; ++k) {
    float bp = myp; int bi = lane;
    for (int off = 32; off > 0; off >>= 1) {
      float op = __shfl_xor(bp, off); int oi = __shfl_xor(bi, off);
      if (op > bp || (op == bp && oi < bi)) { bp = op; bi = oi; }
    }
    gsum += bp;
    if (lane == k) { myg = bp; myi = bi; }
    if (lane == bi) myp = -1.f;
  }
  if (lane < K_TOP) {
    topk_i[n * K_TOP + lane] = myi;
    topk_p[n * K_TOP + lane] = myg / (gsum + 1e-9f);
  }
}

__global__ void __launch_bounds__(256) router_topk2(
    const float* __restrict__ x, const float* __restrict__ rwt,
    const float* __restrict__ bias, int* __restrict__ topk_i,
    float* __restrict__ topk_p) {
  const int wave = threadIdx.x >> 6;
  const int lane = threadIdx.x & 63;
  const int n0 = blockIdx.x * 32 + wave * 8;

  float acc[8];
  #pragma unroll
  for (int t = 0; t < 8; ++t) acc[t] = 0.f;

  const float4* wv4 = (const float4*)rwt;
  #pragma unroll 2
  for (int k4 = 0; k4 < 128; ++k4) {
    float4 w = wv4[k4 * 64 + lane];
    #pragma unroll
    for (int t = 0; t < 8; ++t) {
      float4 xv = *(const float4*)(x + (size_t)(n0 + t) * D_DIM + k4 * 4);
      acc[t] += xv.x * w.x + xv.y * w.y + xv.z * w.z + xv.w * w.w;
    }
  }
  float b = bias[lane];
  #pragma unroll 1
  for (int t = 0; t < 8; ++t)
    softmax_topk_write(acc[t] + b, n0 + t, lane, topk_i, topk_p);
}

// ---------------- per-chunk expert histogram ----------------
__global__ void hist_kernel(const int* __restrict__ topk_i, int* __restrict__ chunk_hist) {
  __shared__ int h[E_NUM];
  const int tid = threadIdx.x;
  if (tid < E_NUM) h[tid] = 0;
  __syncthreads();
  int e = topk_i[blockIdx.x * 256 + tid];
  atomicAdd(&h[e], 1);
  __syncthreads();
  if (tid < E_NUM) chunk_hist[blockIdx.x * E_NUM + tid] = h[tid];
}

// ---------------- exclusive scan over chunks, per expert ----------------
__global__ void scan_kernel(const int* __restrict__ chunk_hist, int* __restrict__ chunk_base) {
  const int e = threadIdx.x;
  int run = 0;
  for (int c = 0; c < NCHUNK; ++c) {
    chunk_base[c * E_NUM + e] = run;
    run += chunk_hist[c * E_NUM + e];
  }
}

// ---------------- dispatch: slot = global stable rank within expert ----------------
__global__ void dispatch_kernel(const int* __restrict__ topk_i, const float* __restrict__ topk_p,
                                const int* __restrict__ chunk_base,
                                int* __restrict__ expert_tok, float* __restrict__ expert_gate,
                                int* __restrict__ entry_row) {
  __shared__ int eid[256];
  const int tid = threadIdx.x;
  const int m = blockIdx.x * 256 + tid;
  const int e = topk_i[m];
  eid[tid] = e;
  __syncthreads();
  int rank = 0;
  for (int t = 0; t < tid; ++t) rank += (eid[t] == e);
  int slot = chunk_base[blockIdx.x * E_NUM + e] + rank;
  int row = -1;
  if (slot < CAP) {
    expert_tok[e * CAP + slot] = m / K_TOP;
    expert_gate[e * CAP + slot] = topk_p[m];
    row = e * CAP + slot;
  }
  if (entry_row) entry_row[m] = row;
}

// ================= FAST PATH =================

// mega prep kernel (all parts independent):
//  blocks [0,2048): x fp32->bf16
//  [2048,2080): transpose rw -> rwt
//  [2080,2464): tok_all[0..TOK_ROUTED) = -1   (replaces memset)
//  [2464,3256): convert_w (792 = 66*12 blocks), dest-linear pre-tiled layout
__global__ void prep_all(const float* __restrict__ x, ushort* __restrict__ xb,
                         const float* __restrict__ rw, float* __restrict__ rwt,
                         int* __restrict__ tok_all,
                         const float* __restrict__ wg_, const float* __restrict__ wu_,
                         const float* __restrict__ wd_, const float* __restrict__ swg,
                         const float* __restrict__ swu, const float* __restrict__ swd,
                         ushort* __restrict__ Wt) {
  int b = blockIdx.x;
  if (b < 2048) {
    size_t idx = (size_t)b * 256 + threadIdx.x;
    const float4* s4 = (const float4*)(x + idx * 8);
    float4 v0 = s4[0], v1 = s4[1];
    short8 o;
    o[0] = f2bf(v0.x); o[1] = f2bf(v0.y); o[2] = f2bf(v0.z); o[3] = f2bf(v0.w);
    o[4] = f2bf(v1.x); o[5] = f2bf(v1.y); o[6] = f2bf(v1.z); o[7] = f2bf(v1.w);
    *(short8*)(xb + idx * 8) = o;
    return;
  }
  if (b < 2080) {
    int idx = (b - 2048) * 256 + threadIdx.x;   // 0..8191 exactly
    int e = idx >> 7, k4 = idx & 127;
    float4 v = *(const float4*)(rw + (size_t)e * D_DIM + k4 * 4);
    *(float4*)(rwt + ((size_t)k4 * 64 + e) * 4) = v;
    return;
  }
  if (b < 2464) {
    int i = (b - 2080) * 256 + threadIdx.x;     // 0..98303 exactly
    tok_all[i] = -1;
    return;
  }
  int cb = b - 2464;
  int e = cb / 12;
  int rem = cb - e * 12;
  int p = rem >> 2, q = rem & 3;
  const float* src;
  if (p == 0)      src = (e < E_NUM) ? wg_ + (size_t)e * 131072 : swg + (size_t)(e - E_NUM) * 131072;
  else if (p == 1) src = (e < E_NUM) ? wu_ + (size_t)e * 131072 : swu + (size_t)(e - E_NUM) * 131072;
  else             src = (e < E_NUM) ? wd_ + (size_t)e * 131072 : swd + (size_t)(e - E_NUM) * 131072;
  ushort* dst = Wt + (size_t)e * EW_STRIDE + (size_t)p * 131072;
  #pragma unroll
  for (int i = 0; i < 16; ++i) {
    int d = q * 32768 + i * 2048 + threadIdx.x * 8;
    int ci = d >> 13;
    int r  = d & 8191;
    int nt = r >> 9;
    int rr = r & 511;
    int k8 = rr >> 7;
    int n  = nt * 16 + ((rr >> 3) & 15);
    size_t srcidx;
    if (p < 2) {
      srcidx = (size_t)n * 512 + ci * 32 + k8 * 8;
    } else {
      int np = ci >> 3, kc = ci & 7;
      srcidx = (size_t)(np * 256 + n) * 256 + kc * 32 + k8 * 8;
    }
    const float4* s4 = (const float4*)(src + srcidx);
    float4 v0 = s4[0], v1 = s4[1];
    short8 o;
    o[0] = f2bf(v0.x); o[1] = f2bf(v0.y); o[2] = f2bf(v0.z); o[3] = f2bf(v0.w);
    o[4] = f2bf(v1.x); o[5] = f2bf(v1.y); o[6] = f2bf(v1.z); o[7] = f2bf(v1.w);
    *(short8*)(dst + d) = o;
  }
}

// Unified FFN v6: 128-token tile, 512 threads (8 waves, 2r x 4c), all-reg operands,
// barrier-free K-loops. Routed blocks (j<96): one expert, epilogue -> eo (bf16).
// Shared blocks (j>=96, 64 of them): BOTH shared experts accumulated, epilogue ->
// plain fp32 stores of 0.5*(o0+o1) into out (each token owned by exactly one block).
// XCD-aware decode; grid MUST be 832 = 8 * 104.
template <bool GATHER>
__global__ void __launch_bounds__(512, 1) ffn_mfma(
    const ushort* __restrict__ xb, const ushort* __restrict__ Wt,
    const int* __restrict__ tok_all, const float* __restrict__ gate_all,
    float* __restrict__ out, ushort* __restrict__ expert_out) {
  int e0, nexp, tbase, tok0;
  {
    int xcd = blockIdx.x & 7;
    int j = blockIdx.x >> 3;          // 0..103
    if (j < 96) {                     // routed: 8 experts x 12 tiles per class
      int ec = j / 12;
      int mt = j - ec * 12;
      e0 = ec * 8 + xcd; nexp = 1;
      tbase = e0 * CAP + mt * 128;
      if (tok_all[tbase] < 0) return;
      tok0 = -1;
    } else {                          // shared: 8 tiles per class (64 total), both experts
      int mt = xcd * 8 + (j - 96);    // 0..63
      e0 = E_NUM; nexp = 2;
      tok0 = mt * 128;
      tbase = -1;
    }
  }

  __shared__ ushort Act[32768];       // 64 KB
  __shared__ int   toks[128];
  __shared__ float gts[128];

  const int tid = threadIdx.x;
  const int lane = tid & 63;
  const int wid = tid >> 6;        // 0..7
  const int wr = wid >> 2;         // 0..1
  const int wc = wid & 3;          // 0..3
  const int rl = lane & 15;
  const int hi = lane >> 4;

  if (tid < 128) {
    if (nexp == 1) {
      int t = tok_all[tbase + tid];
      toks[tid] = t;
      gts[tid] = (t >= 0) ? gate_all[tbase + tid] : 0.f;
    } else {
      toks[tid] = tok0 + tid;
      gts[tid] = 0.5f;
    }
  }
  __syncthreads();

  // per-lane X row pointers: A-fragment row = wr*64 + ri*16 + (lane&15)
  const ushort* xA[4];
  #pragma unroll
  for (int ri = 0; ri < 4; ++ri) {
    int t = toks[wr * 64 + ri * 16 + rl];
    xA[ri] = xb + (size_t)(t < 0 ? 0 : t) * D_DIM + hi * 8;
  }

  auto loadXr = [&](int kc, bf16x8 (&a)[4]) {
    #pragma unroll
    for (int ri = 0; ri < 4; ++ri)
      a[ri] = *(const bf16x8*)(xA[ri] + kc * 32);
  };

  const f32x4 fzero = {0.f, 0.f, 0.f, 0.f};
  f32x4 accd[4][8];
  #pragma unroll
  for (int ri = 0; ri < 4; ++ri)
    #pragma unroll
    for (int bj = 0; bj < 8; ++bj) accd[ri][bj] = fzero;

  #pragma unroll 1
  for (int ei = 0; ei < nexp; ++ei) {
    const ushort* wbase = Wt + (size_t)(e0 + ei) * EW_STRIDE;

    auto loadW = [&](int kc, bf16x8 (&g)[4], bf16x8 (&u)[4]) {
      #pragma unroll
      for (int bi = 0; bi < 4; ++bi) {
        const ushort* p = wbase + kc * 8192 + (wc * 4 + bi) * 512 + lane * 8;
        g[bi] = *(const bf16x8*)p;
        u[bi] = *(const bf16x8*)(p + 131072);
      }
    };

    f32x4 accg[4][4], accu[4][4];
    #pragma unroll
    for (int ri = 0; ri < 4; ++ri)
      #pragma unroll
      for (int bi = 0; bi < 4; ++bi) { accg[ri][bi] = fzero; accu[ri][bi] = fzero; }

    auto guMFMA = [&](bf16x8 (&a)[4], bf16x8 (&g)[4], bf16x8 (&u)[4]) {
      __builtin_amdgcn_s_setprio(1);
      #pragma unroll
      for (int bi = 0; bi < 4; ++bi)
        #pragma unroll
        for (int ri = 0; ri < 4; ++ri) {
          accg[ri][bi] = __builtin_amdgcn_mfma_f32_16x16x32_bf16(a[ri], g[bi], accg[ri][bi], 0, 0, 0);
          accu[ri][bi] = __builtin_amdgcn_mfma_f32_16x16x32_bf16(a[ri], u[bi], accu[ri][bi], 0, 0, 0);
        }
      __builtin_amdgcn_s_setprio(0);
    };

    // ---- fused gate+up: 16 K-steps of 32; barrier-free reg pipeline ----
    {
      bf16x8 gA[4], uA[4], gB[4], uB[4], aA[4], aB[4];
      loadW(0, gA, uA); loadXr(0, aA);
      #pragma unroll 1
      for (int k2 = 0; k2 < 16; k2 += 2) {
        loadW(k2 + 1, gB, uB); loadXr(k2 + 1, aB);
        guMFMA(aA, gA, uA);
        if (k2 + 2 < 16) { loadW(k2 + 2, gA, uA); loadXr(k2 + 2, aA); }
        guMFMA(aB, gB, uB);
      }
    }

    __syncthreads();   // prior down-pass Act reads (ei>0) complete before overwrite

    // ---- silu(g)*u in-register -> Act (fragment-tiled bf16) ----
    #pragma unroll
    for (int ri = 0; ri < 4; ++ri)
      #pragma unroll
      for (int bi = 0; bi < 4; ++bi) {
        int st = (wr * 4 + ri) * 8 + wc * 2 + (bi >> 1);
        int base = st * 512 + ((bi & 1) * 2 + (rl >> 3)) * 128 + (rl & 7);
        #pragma unroll
        for (int j = 0; j < 4; ++j) {
          float g = accg[ri][bi][j], u = accu[ri][bi][j];
          Act[base + (hi * 4 + j) * 8] = f2bf(g / (1.f + __expf(-g)) * u);
        }
      }

    // ---- down: 8 K-steps of 32 over F; barrier-free; accumulates across ei ----
    const ushort* wdbase = wbase + 262144 + (wc >> 1) * 65536 + ((wc & 1) * 8) * 512 + lane * 8;
    auto loadWd = [&](int kc, bf16x8 (&d)[8]) {
      #pragma unroll
      for (int bj = 0; bj < 8; ++bj)
        d[bj] = *(const bf16x8*)(wdbase + kc * 8192 + bj * 512);
    };
    auto dnMFMA = [&](int kc, bf16x8 (&d)[8]) {
      bf16x8 a[4];
      #pragma unroll
      for (int ri = 0; ri < 4; ++ri)
        a[ri] = *(const bf16x8*)(&Act[((wr * 4 + ri) * 8 + kc) * 512 + lane * 8]);
      __builtin_amdgcn_s_setprio(1);
      #pragma unroll
      for (int bj = 0; bj < 8; ++bj)
        #pragma unroll
        for (int ri = 0; ri < 4; ++ri)
          accd[ri][bj] = __builtin_amdgcn_mfma_f32_16x16x32_bf16(a[ri], d[bj], accd[ri][bj], 0, 0, 0);
      __builtin_amdgcn_s_setprio(0);
    };

    bf16x8 dA[8], dB[8];
    loadWd(0, dA);
    __syncthreads();   // Act ready
    #pragma unroll 1
    for (int k2 = 0; k2 < 8; k2 += 2) {
      loadWd(k2 + 1, dB);
      dnMFMA(k2, dA);
      if (k2 + 2 < 8) loadWd(k2 + 2, dA);
      dnMFMA(k2 + 1, dB);
    }
  }

  // ---- epilogue ----
  if (nexp == 2) {
    // shared: sole owner of these token rows -> plain stores (gather seeds from out)
    #pragma unroll
    for (int ri = 0; ri < 4; ++ri)
      #pragma unroll
      for (int j = 0; j < 4; ++j) {
        int r = wr * 64 + ri * 16 + hi * 4 + j;
        int t = tok0 + r;
        float* orow = out + (size_t)t * D_DIM + wc * 128 + rl;
        if (GATHER) {
          #pragma unroll
          for (int bj = 0; bj < 8; ++bj)
            orow[bj * 16] = 0.5f * accd[ri][bj][j];
        } else {
          #pragma unroll
          for (int bj = 0; bj < 8; ++bj)
            atomicAdd(orow + bj * 16, 0.5f * accd[ri][bj][j]);
        }
      }
  } else if (GATHER) {
    #pragma unroll
    for (int ri = 0; ri < 4; ++ri)
      #pragma unroll
      for (int j = 0; j < 4; ++j) {
        int r = wr * 64 + ri * 16 + hi * 4 + j;
        if (toks[r] < 0) continue;
        ushort* erow = expert_out + (size_t)(tbase + r) * D_DIM + wc * 128 + rl;
        #pragma unroll
        for (int bj = 0; bj < 8; ++bj)
          erow[bj * 16] = f2bf(accd[ri][bj][j]);
      }
  } else {
    #pragma unroll
    for (int ri = 0; ri < 4; ++ri)
      #pragma unroll
      for (int j = 0; j < 4; ++j) {
        int r = wr * 64 + ri * 16 + hi * 4 + j;
        int t = toks[r];
        if (t < 0) continue;
        float gt = gts[r];
        float* orow = out + (size_t)t * D_DIM + wc * 128 + rl;
        #pragma unroll
        for (int bj = 0; bj < 8; ++bj)
          atomicAdd(orow + bj * 16, gt * accd[ri][bj][j]);
      }
  }
}

// ---------------- gather combine: one wave per token; seeds from out (shared part) ----------------
__global__ void __launch_bounds__(256) gather_out(
    const ushort* __restrict__ eo, const int* __restrict__ entry_row,
    const float* __restrict__ topk_p, float* __restrict__ out) {
  const int t = blockIdx.x * 4 + (threadIdx.x >> 6);
  const int lane = threadIdx.x & 63;
  const int base = t * K_TOP;

  float4* o = (float4*)(out + (size_t)t * D_DIM + lane * 8);
  float4 o0 = o[0], o1 = o[1];
  float acc[8] = {o0.x, o0.y, o0.z, o0.w, o1.x, o1.y, o1.z, o1.w};

  #pragma unroll
  for (int k = 0; k < K_TOP; ++k) {
    int row = entry_row[base + k];
    if (row >= 0) {
      float g = topk_p[base + k];
      bf16x8 v = *(const bf16x8*)(eo + (size_t)row * D_DIM + lane * 8);
      #pragma unroll
      for (int j = 0; j < 8; ++j) acc[j] += g * bf2f((ushort)v[j]);
    }
  }
  o[0] = make_float4(acc[0], acc[1], acc[2], acc[3]);
  o[1] = make_float4(acc[4], acc[5], acc[6], acc[7]);
}

// ================= LEGACY PATH (round-2, used when ws tiny) =================

__global__ void __launch_bounds__(256, 2) expert_ffn_mfma(
    const float* __restrict__ x, const float* __restrict__ wg_,
    const float* __restrict__ wu_, const float* __restrict__ wd_,
    const int* __restrict__ expert_tok, const float* __restrict__ expert_gate,
    float* __restrict__ out) {
  const int e = blockIdx.x & (E_NUM - 1);
  const int mt = blockIdx.x >> 6;
  const int s0 = mt * 64;
  if (expert_tok[e * CAP + s0] < 0) return;

  __shared__ ushort Xs[64][72];
  __shared__ ushort Ws[256][72];
  __shared__ ushort Act[64][264];
  __shared__ int   toks[64];
  __shared__ float gts[64];

  const int tid = threadIdx.x;
  const int lane = tid & 63;
  const int wid = tid >> 6;
  const int rl = lane & 15;
  const int ko = (lane >> 4) * 8;
  const int rquad = (lane >> 4) * 4;

  if (tid < 64) {
    int t = expert_tok[e * CAP + s0 + tid];
    toks[tid] = t;
    gts[tid] = (t >= 0) ? expert_gate[e * CAP + s0 + tid] : 0.f;
  }
  __syncthreads();

  float4 px[4], pw[16];

  auto loadX = [&](int kb) {
    #pragma unroll
    for (int it = 0; it < 4; ++it) {
      int idx = tid + it * 256;
      int row = idx >> 4, c4 = (idx & 15) << 2;
      int t = toks[row];
      px[it] = (t >= 0) ? *(const float4*)(x + (size_t)t * D_DIM + kb * 64 + c4)
                        : make_float4(0.f, 0.f, 0.f, 0.f);
    }
  };
  auto writeX = [&]() {
    #pragma unroll
    for (int it = 0; it < 4; ++it) {
      int idx = tid + it * 256;
      int row = idx >> 4, c4 = (idx & 15) << 2;
      ushort4 h; h.x = f2bf(px[it].x); h.y = f2bf(px[it].y);
      h.z = f2bf(px[it].z); h.w = f2bf(px[it].w);
      *(ushort4*)&Xs[row][c4] = h;
    }
  };
  auto loadW = [&](const float* src, int ldk, int kb) {
    #pragma unroll
    for (int it = 0; it < 16; ++it) {
      int idx = tid + it * 256;
      int row = idx >> 4, c4 = (idx & 15) << 2;
      pw[it] = *(const float4*)(src + (size_t)row * ldk + kb * 64 + c4);
    }
  };
  auto writeW = [&]() {
    #pragma unroll
    for (int it = 0; it < 16; ++it) {
      int idx = tid + it * 256;
      int row = idx >> 4, c4 = (idx & 15) << 2;
      ushort4 h; h.x = f2bf(pw[it].x); h.y = f2bf(pw[it].y);
      h.z = f2bf(pw[it].z); h.w = f2bf(pw[it].w);
      *(ushort4*)&Ws[row][c4] = h;
    }
  };
  auto compute = [&](const ushort* Ab, int lda, f32x4 (&acc)[4][4]) {
    #pragma unroll
    for (int kk = 0; kk < 2; ++kk) {
      bf16x8 a[4], b[4];
      #pragma unroll
      for (int ri = 0; ri < 4; ++ri)
        a[ri] = *(const bf16x8*)(Ab + (size_t)(ri * 16 + rl) * lda + kk * 32 + ko);
      #pragma unroll
      for (int bi = 0; bi < 4; ++bi)
        b[bi] = *(const bf16x8*)(&Ws[wid * 64 + bi * 16 + rl][kk * 32 + ko]);
      #pragma unroll
      for (int ri = 0; ri < 4; ++ri)
        #pragma unroll
        for (int bi = 0; bi < 4; ++bi)
          acc[ri][bi] = __builtin_amdgcn_mfma_f32_16x16x32_bf16(a[ri], b[bi], acc[ri][bi], 0, 0, 0);
    }
  };

  const f32x4 fzero = {0.f, 0.f, 0.f, 0.f};

  #pragma unroll 1
  for (int which = 0; which < 2; ++which) {
    const float* wsrc = (which == 0 ? wg_ : wu_) + (size_t)e * F_DIM * D_DIM;
    f32x4 acc[4][4];
    #pragma unroll
    for (int ri = 0; ri < 4; ++ri)
      #pragma unroll
      for (int bi = 0; bi < 4; ++bi) acc[ri][bi] = fzero;

    loadX(0); loadW(wsrc, D_DIM, 0);
    writeX(); writeW();
    __syncthreads();
    for (int kb = 0; kb < 8; ++kb) {
      if (kb < 7) { loadX(kb + 1); loadW(wsrc, D_DIM, kb + 1); }
      compute(&Xs[0][0], 72, acc);
      __syncthreads();
      if (kb < 7) { writeX(); writeW(); __syncthreads(); }
    }
    #pragma unroll
    for (int ri = 0; ri < 4; ++ri)
      #pragma unroll
      for (int bi = 0; bi < 4; ++bi)
        #pragma unroll
        for (int j = 0; j < 4; ++j) {
          int r = ri * 16 + rquad + j;
          int c = wid * 64 + bi * 16 + rl;
          if (which == 0) {
            Act[r][c] = f2bf(acc[ri][bi][j]);
          } else {
            float hg = bf2f(Act[r][c]);
            float a = hg / (1.f + __expf(-hg)) * acc[ri][bi][j];
            Act[r][c] = f2bf(a);
          }
        }
    __syncthreads();
  }

  #pragma unroll 1
  for (int np = 0; np < 2; ++np) {
    const float* wsrc = wd_ + ((size_t)e * D_DIM + np * 256) * F_DIM;
    f32x4 acc[4][4];
    #pragma unroll
    for (int ri = 0; ri < 4; ++ri)
      #pragma unroll
      for (int bi = 0; bi < 4; ++bi) acc[ri][bi] = fzero;

    loadW(wsrc, F_DIM, 0); writeW();
    __syncthreads();
    for (int kb = 0; kb < 4; ++kb) {
      if (kb < 3) loadW(wsrc, F_DIM, kb + 1);
      compute(&Act[0][kb * 64], 264, acc);
      __syncthreads();
      if (kb < 3) { writeW(); __syncthreads(); }
    }
    #pragma unroll
    for (int ri = 0; ri < 4; ++ri)
      #pragma unroll
      for (int bi = 0; bi < 4; ++bi)
        #pragma unroll
        for (int j = 0; j < 4; ++j) {
          int r = ri * 16 + rquad + j;
          int t = toks[r];
          if (t >= 0) {
            int c = np * 256 + wid * 64 + bi * 16 + rl;
            atomicAdd(out + (size_t)t * D_DIM + c, gts[r] * acc[ri][bi][j]);
          }
        }
  }
}

__global__ void __launch_bounds__(256, 2) shared_ffn_mfma(
    const float* __restrict__ x, const float* __restrict__ swg,
    const float* __restrict__ swu, const float* __restrict__ swd,
    float* __restrict__ out) {
  const int row0 = blockIdx.x * 32;

  __shared__ ushort Xs[32][72];
  __shared__ ushort Ws[256][72];
  __shared__ ushort Act[32][264];

  const int tid = threadIdx.x;
  const int lane = tid & 63;
  const int wid = tid >> 6;
  const int rl = lane & 15;
  const int ko = (lane >> 4) * 8;
  const int rquad = (lane >> 4) * 4;

  float4 px[2], pw[16];

  auto loadX = [&](int kb) {
    #pragma unroll
    for (int it = 0; it < 2; ++it) {
      int idx = tid + it * 256;
      int row = idx >> 4, c4 = (idx & 15) << 2;
      px[it] = *(const float4*)(x + (size_t)(row0 + row) * D_DIM + kb * 64 + c4);
    }
  };
  auto writeX = [&]() {
    #pragma unroll
    for (int it = 0; it < 2; ++it) {
      int idx = tid + it * 256;
      int row = idx >> 4, c4 = (idx & 15) << 2;
      ushort4 h; h.x = f2bf(px[it].x); h.y = f2bf(px[it].y);
      h.z = f2bf(px[it].z); h.w = f2bf(px[it].w);
      *(ushort4*)&Xs[row][c4] = h;
    }
  };
  auto loadW = [&](const float* src, int ldk, int kb) {
    #pragma unroll
    for (int it = 0; it < 16; ++it) {
      int idx = tid + it * 256;
      int row = idx >> 4, c4 = (idx & 15) << 2;
      pw[it] = *(const float4*)(src + (size_t)row * ldk + kb * 64 + c4);
    }
  };
  auto writeW = [&]() {
    #pragma unroll
    for (int it = 0; it < 16; ++it) {
      int idx = tid + it * 256;
      int row = idx >> 4, c4 = (idx & 15) << 2;
      ushort4 h; h.x = f2bf(pw[it].x); h.y = f2bf(pw[it].y);
      h.z = f2bf(pw[it].z); h.w = f2bf(pw[it].w);
      *(ushort4*)&Ws[row][c4] = h;
    }
  };
  auto compute = [&](const ushort* Ab, int lda, f32x4 (&acc)[2][4]) {
    #pragma unroll
    for (int kk = 0; kk < 2; ++kk) {
      bf16x8 a[2], b[4];
      #pragma unroll
      for (int ri = 0; ri < 2; ++ri)
        a[ri] = *(const bf16x8*)(Ab + (size_t)(ri * 16 + rl) * lda + kk * 32 + ko);
      #pragma unroll
      for (int bi = 0; bi < 4; ++bi)
        b[bi] = *(const bf16x8*)(&Ws[wid * 64 + bi * 16 + rl][kk * 32 + ko]);
      #pragma unroll
      for (int ri = 0; ri < 2; ++ri)
        #pragma unroll
        for (int bi = 0; bi < 4; ++bi)
          acc[ri][bi] = __builtin_amdgcn_mfma_f32_16x16x32_bf16(a[ri], b[bi], acc[ri][bi], 0, 0, 0);
    }
  };

  const f32x4 fzero = {0.f, 0.f, 0.f, 0.f};
  f32x4 accd[2][2][4];
  #pragma unroll
  for (int np = 0; np < 2; ++np)
    #pragma unroll
    for (int ri = 0; ri < 2; ++ri)
      #pragma unroll
      for (int bi = 0; bi < 4; ++bi) accd[np][ri][bi] = fzero;

  #pragma unroll 1
  for (int sh = 0; sh < SH_NUM; ++sh) {
    #pragma unroll 1
    for (int which = 0; which < 2; ++which) {
      const float* wsrc = (which == 0 ? swg : swu) + (size_t)sh * F_DIM * D_DIM;
      f32x4 acc[2][4];
      #pragma unroll
      for (int ri = 0; ri < 2; ++ri)
        #pragma unroll
        for (int bi = 0; bi < 4; ++bi) acc[ri][bi] = fzero;

      loadX(0); loadW(wsrc, D_DIM, 0);
      writeX(); writeW();
      __syncthreads();
      for (int kb = 0; kb < 8; ++kb) {
        if (kb < 7) { loadX(kb + 1); loadW(wsrc, D_DIM, kb + 1); }
        compute(&Xs[0][0], 72, acc);
        __syncthreads();
        if (kb < 7) { writeX(); writeW(); __syncthreads(); }
      }
      #pragma unroll
      for (int ri = 0; ri < 2; ++ri)
        #pragma unroll
        for (int bi = 0; bi < 4; ++bi)
          #pragma unroll
          for (int j = 0; j < 4; ++j) {
            int r = ri * 16 + rquad + j;
            int c = wid * 64 + bi * 16 + rl;
            if (which == 0) {
              Act[r][c] = f2bf(acc[ri][bi][j]);
            } else {
              float hg = bf2f(Act[r][c]);
              float a = hg / (1.f + __expf(-hg)) * acc[ri][bi][j];
              Act[r][c] = f2bf(a);
            }
          }
      __syncthreads();
    }
    #pragma unroll
    for (int np = 0; np < 2; ++np) {
      const float* wsrc = swd + ((size_t)sh * D_DIM + np * 256) * F_DIM;
      loadW(wsrc, F_DIM, 0); writeW();
      __syncthreads();
      for (int kb = 0; kb < 4; ++kb) {
        if (kb < 3) loadW(wsrc, F_DIM, kb + 1);
        compute(&Act[0][kb * 64], 264, accd[np]);
        __syncthreads();
        if (kb < 3) { writeW(); __syncthreads(); }
      }
    }
  }

  #pragma unroll
  for (int np = 0; np < 2; ++np)
    #pragma unroll
    for (int ri = 0; ri < 2; ++ri)
      #pragma unroll
      for (int bi = 0; bi < 4; ++bi)
        #pragma unroll
        for (int j = 0; j < 4; ++j) {
          int r = ri * 16 + rquad + j;
          int c = np * 256 + wid * 64 + bi * 16 + rl;
          out[(size_t)(row0 + r) * D_DIM + c] = 0.5f * accd[np][ri][bi][j];
        }
}

extern "C" void kernel_launch(void* const* d_in, const int* in_sizes, int n_in,
                              void* d_out, int out_size, void* d_ws, size_t ws_size,
                              hipStream_t stream) {
  const float* x    = (const float*)d_in[0];
  const float* rw   = (const float*)d_in[1];
  const float* bias = (const float*)d_in[2];
  const float* swg  = (const float*)d_in[3];
  const float* swu  = (const float*)d_in[4];
  const float* swd  = (const float*)d_in[5];
  const float* wg   = (const float*)d_in[6];
  const float* wu   = (const float*)d_in[7];
  const float* wd   = (const float*)d_in[8];
  float* out = (float*)d_out;

  const size_t small = 2 * (size_t)M_ENT * 4 + (size_t)M_ENT * 4 +
                       2 * (size_t)NCHUNK * E_NUM * 4 + 2 * (size_t)TOK_TOTAL * 4 +
                       RWT_BYTES;
  const size_t need_mid = X_BF_BYTES + WT_BYTES + small;
  const size_t need_big = need_mid + EO_BYTES;

  if (ws_size >= need_mid) {
    const bool gather = (ws_size >= need_big);
    char* ws = (char*)d_ws;
    ushort* x_bf     = (ushort*)ws; ws += X_BF_BYTES;
    ushort* Wt       = (ushort*)ws; ws += WT_BYTES;
    int*   topk_i    = (int*)ws;    ws += (size_t)M_ENT * 4;
    float* topk_p    = (float*)ws;  ws += (size_t)M_ENT * 4;
    int*   entry_row = (int*)ws;    ws += (size_t)M_ENT * 4;
    int*   chunk_hist= (int*)ws;    ws += (size_t)NCHUNK * E_NUM * 4;
    int*   chunk_base= (int*)ws;    ws += (size_t)NCHUNK * E_NUM * 4;
    int*   tok_all   = (int*)ws;    ws += (size_t)TOK_TOTAL * 4;
    float* gate_all  = (float*)ws;  ws += (size_t)TOK_TOTAL * 4;
    float* rwt       = (float*)ws;  ws += RWT_BYTES;
    ushort* eo       = (ushort*)ws; // only valid if gather

    prep_all<<<3256, 256, 0, stream>>>(x, x_bf, rw, rwt, tok_all,
                                       wg, wu, wd, swg, swu, swd, Wt);
    router_topk2<<<256, 256, 0, stream>>>(x, rwt, bias, topk_i, topk_p);
    if (!gather) hipMemsetAsync(out, 0, (size_t)out_size * 4, stream);
    hist_kernel<<<NCHUNK, 256, 0, stream>>>(topk_i, chunk_hist);
    scan_kernel<<<1, 64, 0, stream>>>(chunk_hist, chunk_base);
    dispatch_kernel<<<NCHUNK, 256, 0, stream>>>(topk_i, topk_p, chunk_base, tok_all,
                                                gate_all, entry_row);
    const int nblk = (CAP / 128) * E_NUM + N_TOK / 128;   // 768 + 64 = 832 = 8*104
    if (gather) {
      ffn_mfma<true><<<nblk, 512, 0, stream>>>(x_bf, Wt, tok_all, gate_all, out, eo);
      gather_out<<<N_TOK / 4, 256, 0, stream>>>(eo, entry_row, topk_p, out);
    } else {
      ffn_mfma<false><<<nblk, 512, 0, stream>>>(x_bf, Wt, tok_all, gate_all, out, nullptr);
    }
  } else {
    char* ws = (char*)d_ws;
    int*   topk_i      = (int*)ws;   ws += (size_t)M_ENT * 4;
    float* topk_p      = (float*)ws; ws += (size_t)M_ENT * 4;
    int*   chunk_hist  = (int*)ws;   ws += (size_t)NCHUNK * E_NUM * 4;
    int*   chunk_base  = (int*)ws;   ws += (size_t)NCHUNK * E_NUM * 4;
    int*   expert_tok  = (int*)ws;   ws += (size_t)E_NUM * CAP * 4;
    float* expert_gate = (float*)ws; ws += (size_t)E_NUM * CAP * 4;

    router_topk<<<N_TOK / 4, 256, 0, stream>>>(x, rw, bias, topk_i, topk_p);
    hipMemsetAsync(expert_tok, 0xFF, (size_t)E_NUM * CAP * 4, stream);
    hist_kernel<<<NCHUNK, 256, 0, stream>>>(topk_i, chunk_hist);
    scan_kernel<<<1, 64, 0, stream>>>(chunk_hist, chunk_base);
    dispatch_kernel<<<NCHUNK, 256, 0, stream>>>(topk_i, topk_p, chunk_base, expert_tok,
                                                expert_gate, nullptr);
    shared_ffn_mfma<<<N_TOK / 32, 256, 0, stream>>>(x, swg, swu, swd, out);
    expert_ffn_mfma<<<(CAP / 64) * E_NUM, 256, 0, stream>>>(x, wg, wu, wd, expert_tok,
                                                            expert_gate, out);
  }
}

// Round 14
// 265.100 us; speedup vs baseline: 1.4285x; 1.4285x over previous
//
#include <hip/hip_runtime.h>
#include <hip/hip_bf16.h>
#include <math.h>

#define N_TOK 8192
#define D_DIM 512
#define F_DIM 256
#define E_NUM 64
#define SH_NUM 2
#define K_TOP 6
#define CAP   1536
#define M_ENT (N_TOK * K_TOP)   // 49152
#define NCHUNK (M_ENT / 256)    // 192

#define EW_STRIDE 393216            // shorts per expert blob (48 chunks x 8192)
#define E_TOT (E_NUM + SH_NUM)      // 66
#define X_BF_BYTES   (8388608ull)
#define WT_BYTES     ((size_t)E_TOT * EW_STRIDE * 2)
#define TOK_ROUTED   (E_NUM * CAP)                   // 98304
#define TOK_TOTAL    (TOK_ROUTED + SH_NUM * N_TOK)   // 114688
#define EO_BYTES     ((size_t)TOK_TOTAL * D_DIM * 2)
#define RWT_BYTES    131072ull

typedef __attribute__((ext_vector_type(8))) short bf16x8;
typedef __attribute__((ext_vector_type(8))) short short8;
typedef __attribute__((ext_vector_type(4))) float f32x4;

__device__ __forceinline__ ushort f2bf(float f) {
  union { float f; unsigned u; } c; c.f = f;
  return (ushort)((c.u + 0x7FFFu + ((c.u >> 16) & 1u)) >> 16);
}
__device__ __forceinline__ float bf2f(ushort h) {
  union { unsigned u; float f; } c; c.u = ((unsigned)h) << 16;
  return c.f;
}

// ---------------- legacy router (small-ws path) ----------------
__global__ void router_topk(const float* __restrict__ x, const float* __restrict__ rw,
                            const float* __restrict__ bias, int* __restrict__ topk_i,
                            float* __restrict__ topk_p) {
  const int wave = threadIdx.x >> 6;
  const int lane = threadIdx.x & 63;
  const int n = blockIdx.x * 4 + wave;
  if (n >= N_TOK) return;

  const float4* xr = (const float4*)(x + (size_t)n * D_DIM);
  const float4* wr = (const float4*)(rw + (size_t)lane * D_DIM);
  float acc = 0.f;
  #pragma unroll 4
  for (int d4 = 0; d4 < D_DIM / 4; ++d4) {
    float4 xv = xr[d4]; float4 wv = wr[d4];
    acc += xv.x * wv.x + xv.y * wv.y + xv.z * wv.z + xv.w * wv.w;
  }
  float logit = acc + bias[lane];

  float m = logit;
  for (int off = 32; off > 0; off >>= 1) m = fmaxf(m, __shfl_xor(m, off));
  float p = expf(logit - m);
  float s = p;
  for (int off = 32; off > 0; off >>= 1) s += __shfl_xor(s, off);
  float prob = p / s;

  float myp = prob;
  float gsum = 0.f;
  float myg = 0.f; int myi = -1;
  for (int k = 0; k < K_TOP; ++k) {
    float bp = myp; int bi = lane;
    for (int off = 32; off > 0; off >>= 1) {
      float op = __shfl_xor(bp, off); int oi = __shfl_xor(bi, off);
      if (op > bp || (op == bp && oi < bi)) { bp = op; bi = oi; }
    }
    gsum += bp;
    if (lane == k) { myg = bp; myi = bi; }
    if (lane == bi) myp = -1.f;
  }
  if (lane < K_TOP) {
    topk_i[n * K_TOP + lane] = myi;
    topk_p[n * K_TOP + lane] = myg / (gsum + 1e-9f);
  }
}

__device__ __forceinline__ void softmax_topk_write(float logit, int n, int lane,
                                                   int* __restrict__ topk_i,
                                                   float* __restrict__ topk_p) {
  float m = logit;
  for (int off = 32; off > 0; off >>= 1) m = fmaxf(m, __shfl_xor(m, off));
  float p = expf(logit - m);
  float s = p;
  for (int off = 32; off > 0; off >>= 1) s += __shfl_xor(s, off);
  float prob = p / s;

  float myp = prob;
  float gsum = 0.f;
  float myg = 0.f; int myi = -1;
  #pragma unroll 1
  for (int k = 0; k < K_TOP; ++k) {
    float bp = myp; int bi = lane;
    for (int off = 32; off > 0; off >>= 1) {
      float op = __shfl_xor(bp, off); int oi = __shfl_xor(bi, off);
      if (op > bp || (op == bp && oi < bi)) { bp = op; bi = oi; }
    }
    gsum += bp;
    if (lane == k) { myg = bp; myi = bi; }
    if (lane == bi) myp = -1.f;
  }
  if (lane < K_TOP) {
    topk_i[n * K_TOP + lane] = myi;
    topk_p[n * K_TOP + lane] = myg / (gsum + 1e-9f);
  }
}

__global__ void __launch_bounds__(256) router_topk2(
    const float* __restrict__ x, const float* __restrict__ rwt,
    const float* __restrict__ bias, int* __restrict__ topk_i,
    float* __restrict__ topk_p) {
  const int wave = threadIdx.x >> 6;
  const int lane = threadIdx.x & 63;
  const int n0 = blockIdx.x * 32 + wave * 8;

  float acc[8];
  #pragma unroll
  for (int t = 0; t < 8; ++t) acc[t] = 0.f;

  const float4* wv4 = (const float4*)rwt;
  #pragma unroll 2
  for (int k4 = 0; k4 < 128; ++k4) {
    float4 w = wv4[k4 * 64 + lane];
    #pragma unroll
    for (int t = 0; t < 8; ++t) {
      float4 xv = *(const float4*)(x + (size_t)(n0 + t) * D_DIM + k4 * 4);
      acc[t] += xv.x * w.x + xv.y * w.y + xv.z * w.z + xv.w * w.w;
    }
  }
  float b = bias[lane];
  #pragma unroll 1
  for (int t = 0; t < 8; ++t)
    softmax_topk_write(acc[t] + b, n0 + t, lane, topk_i, topk_p);
}

// ---------------- per-chunk expert histogram ----------------
__global__ void hist_kernel(const int* __restrict__ topk_i, int* __restrict__ chunk_hist) {
  __shared__ int h[E_NUM];
  const int tid = threadIdx.x;
  if (tid < E_NUM) h[tid] = 0;
  __syncthreads();
  int e = topk_i[blockIdx.x * 256 + tid];
  atomicAdd(&h[e], 1);
  __syncthreads();
  if (tid < E_NUM) chunk_hist[blockIdx.x * E_NUM + tid] = h[tid];
}

// ---------------- exclusive scan over chunks, per expert ----------------
__global__ void scan_kernel(const int* __restrict__ chunk_hist, int* __restrict__ chunk_base) {
  const int e = threadIdx.x;
  int run = 0;
  for (int c = 0; c < NCHUNK; ++c) {
    chunk_base[c * E_NUM + e] = run;
    run += chunk_hist[c * E_NUM + e];
  }
}

// ---------------- dispatch: slot = global stable rank within expert ----------------
__global__ void dispatch_kernel(const int* __restrict__ topk_i, const float* __restrict__ topk_p,
                                const int* __restrict__ chunk_base,
                                int* __restrict__ expert_tok, float* __restrict__ expert_gate,
                                int* __restrict__ entry_row) {
  __shared__ int eid[256];
  const int tid = threadIdx.x;
  const int m = blockIdx.x * 256 + tid;
  const int e = topk_i[m];
  eid[tid] = e;
  __syncthreads();
  int rank = 0;
  for (int t = 0; t < tid; ++t) rank += (eid[t] == e);
  int slot = chunk_base[blockIdx.x * E_NUM + e] + rank;
  int row = -1;
  if (slot < CAP) {
    expert_tok[e * CAP + slot] = m / K_TOP;
    expert_gate[e * CAP + slot] = topk_p[m];
    row = e * CAP + slot;
  }
  if (entry_row) entry_row[m] = row;
}

// ================= FAST PATH =================

// mega prep kernel (all parts independent):
//  [0,2048): x fp32->bf16
//  [2048,2080): transpose rw -> rwt
//  [2080,2464): tok_all[0..TOK_ROUTED) = -1   (replaces memset)
//  [2464,2528): shared token list init (tok, gate=0.5)
//  [2528,3320): convert_w (792 = 66*12 blocks), dest-linear pre-tiled layout
__global__ void prep_all(const float* __restrict__ x, ushort* __restrict__ xb,
                         const float* __restrict__ rw, float* __restrict__ rwt,
                         int* __restrict__ tok_all, float* __restrict__ gate_all,
                         const float* __restrict__ wg_, const float* __restrict__ wu_,
                         const float* __restrict__ wd_, const float* __restrict__ swg,
                         const float* __restrict__ swu, const float* __restrict__ swd,
                         ushort* __restrict__ Wt) {
  int b = blockIdx.x;
  if (b < 2048) {
    size_t idx = (size_t)b * 256 + threadIdx.x;
    const float4* s4 = (const float4*)(x + idx * 8);
    float4 v0 = s4[0], v1 = s4[1];
    short8 o;
    o[0] = f2bf(v0.x); o[1] = f2bf(v0.y); o[2] = f2bf(v0.z); o[3] = f2bf(v0.w);
    o[4] = f2bf(v1.x); o[5] = f2bf(v1.y); o[6] = f2bf(v1.z); o[7] = f2bf(v1.w);
    *(short8*)(xb + idx * 8) = o;
    return;
  }
  if (b < 2080) {
    int idx = (b - 2048) * 256 + threadIdx.x;   // 0..8191 exactly
    int e = idx >> 7, k4 = idx & 127;
    float4 v = *(const float4*)(rw + (size_t)e * D_DIM + k4 * 4);
    *(float4*)(rwt + ((size_t)k4 * 64 + e) * 4) = v;
    return;
  }
  if (b < 2464) {
    int i = (b - 2080) * 256 + threadIdx.x;     // 0..98303 exactly
    tok_all[i] = -1;
    return;
  }
  if (b < 2528) {
    int i = (b - 2464) * 256 + threadIdx.x;     // 0..16383 exactly
    tok_all[TOK_ROUTED + i] = i & (N_TOK - 1);
    gate_all[TOK_ROUTED + i] = 0.5f;
    return;
  }
  int cb = b - 2528;
  int e = cb / 12;
  int rem = cb - e * 12;
  int p = rem >> 2, q = rem & 3;
  const float* src;
  if (p == 0)      src = (e < E_NUM) ? wg_ + (size_t)e * 131072 : swg + (size_t)(e - E_NUM) * 131072;
  else if (p == 1) src = (e < E_NUM) ? wu_ + (size_t)e * 131072 : swu + (size_t)(e - E_NUM) * 131072;
  else             src = (e < E_NUM) ? wd_ + (size_t)e * 131072 : swd + (size_t)(e - E_NUM) * 131072;
  ushort* dst = Wt + (size_t)e * EW_STRIDE + (size_t)p * 131072;
  #pragma unroll
  for (int i = 0; i < 16; ++i) {
    int d = q * 32768 + i * 2048 + threadIdx.x * 8;
    int ci = d >> 13;
    int r  = d & 8191;
    int nt = r >> 9;
    int rr = r & 511;
    int k8 = rr >> 7;
    int n  = nt * 16 + ((rr >> 3) & 15);
    size_t srcidx;
    if (p < 2) {
      srcidx = (size_t)n * 512 + ci * 32 + k8 * 8;
    } else {
      int np = ci >> 3, kc = ci & 7;
      srcidx = (size_t)(np * 256 + n) * 256 + kc * 32 + k8 * 8;
    }
    const float4* s4 = (const float4*)(src + srcidx);
    float4 v0 = s4[0], v1 = s4[1];
    short8 o;
    o[0] = f2bf(v0.x); o[1] = f2bf(v0.y); o[2] = f2bf(v0.z); o[3] = f2bf(v0.w);
    o[4] = f2bf(v1.x); o[5] = f2bf(v1.y); o[6] = f2bf(v1.z); o[7] = f2bf(v1.w);
    *(short8*)(dst + d) = o;
  }
}

// Unified FFN v5 (round-12 structure, best known): 128-token tile, 512 threads
// (8 waves, 2r x 4c). ALL operands global->reg, barrier-free K-loops, one expert
// per block. XCD-aware decode; grid MUST be 896 = 8 * 112.
template <bool GATHER>
__global__ void __launch_bounds__(512, 1) ffn_mfma(
    const ushort* __restrict__ xb, const ushort* __restrict__ Wt,
    const int* __restrict__ tok_all, const float* __restrict__ gate_all,
    float* __restrict__ out, ushort* __restrict__ expert_out) {
  int e, tbase;
  {
    int xcd = blockIdx.x & 7;
    int j = blockIdx.x >> 3;          // 0..111
    if (j < 96) {                     // routed: 8 experts x 12 tiles per class
      int ec = j / 12;
      int mt = j - ec * 12;
      e = ec * 8 + xcd;
      tbase = e * CAP + mt * 128;
      if (tok_all[tbase] < 0) return;
    } else {                          // shared: 16 tiles per class (128 total)
      int s = xcd * 16 + (j - 96);
      int sh = s & 1, mt = s >> 1;
      e = E_NUM + sh;
      tbase = TOK_ROUTED + sh * N_TOK + mt * 128;
    }
  }
  const ushort* wbase = Wt + (size_t)e * EW_STRIDE;

  __shared__ ushort Act[32768];       // 64 KB
  __shared__ int   toks[128];
  __shared__ float gts[128];

  const int tid = threadIdx.x;
  const int lane = tid & 63;
  const int wid = tid >> 6;        // 0..7
  const int wr = wid >> 2;         // 0..1
  const int wc = wid & 3;          // 0..3
  const int rl = lane & 15;
  const int hi = lane >> 4;

  if (tid < 128) {
    int t = tok_all[tbase + tid];
    toks[tid] = t;
    gts[tid] = (t >= 0) ? gate_all[tbase + tid] : 0.f;
  }
  __syncthreads();

  // per-lane X row pointers: A-fragment row = wr*64 + ri*16 + (lane&15)
  const ushort* xA[4];
  #pragma unroll
  for (int ri = 0; ri < 4; ++ri) {
    int t = toks[wr * 64 + ri * 16 + rl];
    xA[ri] = xb + (size_t)(t < 0 ? 0 : t) * D_DIM + hi * 8;
  }

  auto loadXr = [&](int kc, bf16x8 (&a)[4]) {
    #pragma unroll
    for (int ri = 0; ri < 4; ++ri)
      a[ri] = *(const bf16x8*)(xA[ri] + kc * 32);
  };
  auto loadW = [&](int kc, bf16x8 (&g)[4], bf16x8 (&u)[4]) {
    #pragma unroll
    for (int bi = 0; bi < 4; ++bi) {
      const ushort* p = wbase + kc * 8192 + (wc * 4 + bi) * 512 + lane * 8;
      g[bi] = *(const bf16x8*)p;
      u[bi] = *(const bf16x8*)(p + 131072);
    }
  };

  const f32x4 fzero = {0.f, 0.f, 0.f, 0.f};
  f32x4 accg[4][4], accu[4][4];
  #pragma unroll
  for (int ri = 0; ri < 4; ++ri)
    #pragma unroll
    for (int bi = 0; bi < 4; ++bi) { accg[ri][bi] = fzero; accu[ri][bi] = fzero; }

  auto guMFMA = [&](bf16x8 (&a)[4], bf16x8 (&g)[4], bf16x8 (&u)[4]) {
    __builtin_amdgcn_s_setprio(1);
    #pragma unroll
    for (int bi = 0; bi < 4; ++bi)
      #pragma unroll
      for (int ri = 0; ri < 4; ++ri) {
        accg[ri][bi] = __builtin_amdgcn_mfma_f32_16x16x32_bf16(a[ri], g[bi], accg[ri][bi], 0, 0, 0);
        accu[ri][bi] = __builtin_amdgcn_mfma_f32_16x16x32_bf16(a[ri], u[bi], accu[ri][bi], 0, 0, 0);
      }
    __builtin_amdgcn_s_setprio(0);
  };

  // ---- fused gate+up: 16 K-steps of 32; barrier-free reg pipeline ----
  {
    bf16x8 gA[4], uA[4], gB[4], uB[4], aA[4], aB[4];
    loadW(0, gA, uA); loadXr(0, aA);
    #pragma unroll 1
    for (int k2 = 0; k2 < 16; k2 += 2) {
      loadW(k2 + 1, gB, uB); loadXr(k2 + 1, aB);
      guMFMA(aA, gA, uA);
      if (k2 + 2 < 16) { loadW(k2 + 2, gA, uA); loadXr(k2 + 2, aA); }
      guMFMA(aB, gB, uB);
    }
  }

  // ---- silu(g)*u in-register -> Act (fragment-tiled bf16) ----
  #pragma unroll
  for (int ri = 0; ri < 4; ++ri)
    #pragma unroll
    for (int bi = 0; bi < 4; ++bi) {
      int st = (wr * 4 + ri) * 8 + wc * 2 + (bi >> 1);
      int base = st * 512 + ((bi & 1) * 2 + (rl >> 3)) * 128 + (rl & 7);
      #pragma unroll
      for (int j = 0; j < 4; ++j) {
        float g = accg[ri][bi][j], u = accu[ri][bi][j];
        Act[base + (hi * 4 + j) * 8] = f2bf(g / (1.f + __expf(-g)) * u);
      }
    }

  // ---- down: out[128 x 512], 8 K-steps of 32 over F; barrier-free ----
  const ushort* wdbase = wbase + 262144 + (wc >> 1) * 65536 + ((wc & 1) * 8) * 512 + lane * 8;
  auto loadWd = [&](int kc, bf16x8 (&d)[8]) {
    #pragma unroll
    for (int bj = 0; bj < 8; ++bj)
      d[bj] = *(const bf16x8*)(wdbase + kc * 8192 + bj * 512);
  };

  f32x4 accd[4][8];
  #pragma unroll
  for (int ri = 0; ri < 4; ++ri)
    #pragma unroll
    for (int bj = 0; bj < 8; ++bj) accd[ri][bj] = fzero;

  bf16x8 dA[8], dB[8];
  loadWd(0, dA);
  __syncthreads();   // Act ready

  auto dnMFMA = [&](int kc, bf16x8 (&d)[8]) {
    bf16x8 a[4];
    #pragma unroll
    for (int ri = 0; ri < 4; ++ri)
      a[ri] = *(const bf16x8*)(&Act[((wr * 4 + ri) * 8 + kc) * 512 + lane * 8]);
    __builtin_amdgcn_s_setprio(1);
    #pragma unroll
    for (int bj = 0; bj < 8; ++bj)
      #pragma unroll
      for (int ri = 0; ri < 4; ++ri)
        accd[ri][bj] = __builtin_amdgcn_mfma_f32_16x16x32_bf16(a[ri], d[bj], accd[ri][bj], 0, 0, 0);
    __builtin_amdgcn_s_setprio(0);
  };

  #pragma unroll 1
  for (int k2 = 0; k2 < 8; k2 += 2) {
    loadWd(k2 + 1, dB);
    dnMFMA(k2, dA);
    if (k2 + 2 < 8) loadWd(k2 + 2, dA);
    dnMFMA(k2 + 1, dB);
  }

  // ---- epilogue ----
  if (GATHER) {
    #pragma unroll
    for (int ri = 0; ri < 4; ++ri)
      #pragma unroll
      for (int j = 0; j < 4; ++j) {
        int r = wr * 64 + ri * 16 + hi * 4 + j;
        if (toks[r] < 0) continue;
        ushort* erow = expert_out + (size_t)(tbase + r) * D_DIM + wc * 128 + rl;
        #pragma unroll
        for (int bj = 0; bj < 8; ++bj)
          erow[bj * 16] = f2bf(accd[ri][bj][j]);
      }
  } else {
    #pragma unroll
    for (int ri = 0; ri < 4; ++ri)
      #pragma unroll
      for (int j = 0; j < 4; ++j) {
        int r = wr * 64 + ri * 16 + hi * 4 + j;
        int t = toks[r];
        if (t < 0) continue;
        float gt = gts[r];
        float* orow = out + (size_t)t * D_DIM + wc * 128 + rl;
        #pragma unroll
        for (int bj = 0; bj < 8; ++bj)
          atomicAdd(orow + bj * 16, gt * accd[ri][bj][j]);
      }
  }
}

// ---------------- gather combine: one wave per token ----------------
__global__ void __launch_bounds__(256) gather_out(
    const ushort* __restrict__ eo, const int* __restrict__ entry_row,
    const float* __restrict__ topk_p, float* __restrict__ out) {
  const int t = blockIdx.x * 4 + (threadIdx.x >> 6);
  const int lane = threadIdx.x & 63;
  const int base = t * K_TOP;

  float acc[8];
  #pragma unroll
  for (int j = 0; j < 8; ++j) acc[j] = 0.f;

  #pragma unroll
  for (int k = 0; k < K_TOP; ++k) {
    int row = entry_row[base + k];
    if (row >= 0) {
      float g = topk_p[base + k];
      bf16x8 v = *(const bf16x8*)(eo + (size_t)row * D_DIM + lane * 8);
      #pragma unroll
      for (int j = 0; j < 8; ++j) acc[j] += g * bf2f((ushort)v[j]);
    }
  }
  #pragma unroll
  for (int sh = 0; sh < SH_NUM; ++sh) {
    int row = TOK_ROUTED + sh * N_TOK + t;
    bf16x8 v = *(const bf16x8*)(eo + (size_t)row * D_DIM + lane * 8);
    #pragma unroll
    for (int j = 0; j < 8; ++j) acc[j] += 0.5f * bf2f((ushort)v[j]);
  }
  float4* o = (float4*)(out + (size_t)t * D_DIM + lane * 8);
  o[0] = make_float4(acc[0], acc[1], acc[2], acc[3]);
  o[1] = make_float4(acc[4], acc[5], acc[6], acc[7]);
}

// ================= LEGACY PATH (round-2, used when ws tiny) =================

__global__ void __launch_bounds__(256, 2) expert_ffn_mfma(
    const float* __restrict__ x, const float* __restrict__ wg_,
    const float* __restrict__ wu_, const float* __restrict__ wd_,
    const int* __restrict__ expert_tok, const float* __restrict__ expert_gate,
    float* __restrict__ out) {
  const int e = blockIdx.x & (E_NUM - 1);
  const int mt = blockIdx.x >> 6;
  const int s0 = mt * 64;
  if (expert_tok[e * CAP + s0] < 0) return;

  __shared__ ushort Xs[64][72];
  __shared__ ushort Ws[256][72];
  __shared__ ushort Act[64][264];
  __shared__ int   toks[64];
  __shared__ float gts[64];

  const int tid = threadIdx.x;
  const int lane = tid & 63;
  const int wid = tid >> 6;
  const int rl = lane & 15;
  const int ko = (lane >> 4) * 8;
  const int rquad = (lane >> 4) * 4;

  if (tid < 64) {
    int t = expert_tok[e * CAP + s0 + tid];
    toks[tid] = t;
    gts[tid] = (t >= 0) ? expert_gate[e * CAP + s0 + tid] : 0.f;
  }
  __syncthreads();

  float4 px[4], pw[16];

  auto loadX = [&](int kb) {
    #pragma unroll
    for (int it = 0; it < 4; ++it) {
      int idx = tid + it * 256;
      int row = idx >> 4, c4 = (idx & 15) << 2;
      int t = toks[row];
      px[it] = (t >= 0) ? *(const float4*)(x + (size_t)t * D_DIM + kb * 64 + c4)
                        : make_float4(0.f, 0.f, 0.f, 0.f);
    }
  };
  auto writeX = [&]() {
    #pragma unroll
    for (int it = 0; it < 4; ++it) {
      int idx = tid + it * 256;
      int row = idx >> 4, c4 = (idx & 15) << 2;
      ushort4 h; h.x = f2bf(px[it].x); h.y = f2bf(px[it].y);
      h.z = f2bf(px[it].z); h.w = f2bf(px[it].w);
      *(ushort4*)&Xs[row][c4] = h;
    }
  };
  auto loadW = [&](const float* src, int ldk, int kb) {
    #pragma unroll
    for (int it = 0; it < 16; ++it) {
      int idx = tid + it * 256;
      int row = idx >> 4, c4 = (idx & 15) << 2;
      pw[it] = *(const float4*)(src + (size_t)row * ldk + kb * 64 + c4);
    }
  };
  auto writeW = [&]() {
    #pragma unroll
    for (int it = 0; it < 16; ++it) {
      int idx = tid + it * 256;
      int row = idx >> 4, c4 = (idx & 15) << 2;
      ushort4 h; h.x = f2bf(pw[it].x); h.y = f2bf(pw[it].y);
      h.z = f2bf(pw[it].z); h.w = f2bf(pw[it].w);
      *(ushort4*)&Ws[row][c4] = h;
    }
  };
  auto compute = [&](const ushort* Ab, int lda, f32x4 (&acc)[4][4]) {
    #pragma unroll
    for (int kk = 0; kk < 2; ++kk) {
      bf16x8 a[4], b[4];
      #pragma unroll
      for (int ri = 0; ri < 4; ++ri)
        a[ri] = *(const bf16x8*)(Ab + (size_t)(ri * 16 + rl) * lda + kk * 32 + ko);
      #pragma unroll
      for (int bi = 0; bi < 4; ++bi)
        b[bi] = *(const bf16x8*)(&Ws[wid * 64 + bi * 16 + rl][kk * 32 + ko]);
      #pragma unroll
      for (int ri = 0; ri < 4; ++ri)
        #pragma unroll
        for (int bi = 0; bi < 4; ++bi)
          acc[ri][bi] = __builtin_amdgcn_mfma_f32_16x16x32_bf16(a[ri], b[bi], acc[ri][bi], 0, 0, 0);
    }
  };

  const f32x4 fzero = {0.f, 0.f, 0.f, 0.f};

  #pragma unroll 1
  for (int which = 0; which < 2; ++which) {
    const float* wsrc = (which == 0 ? wg_ : wu_) + (size_t)e * F_DIM * D_DIM;
    f32x4 acc[4][4];
    #pragma unroll
    for (int ri = 0; ri < 4; ++ri)
      #pragma unroll
      for (int bi = 0; bi < 4; ++bi) acc[ri][bi] = fzero;

    loadX(0); loadW(wsrc, D_DIM, 0);
    writeX(); writeW();
    __syncthreads();
    for (int kb = 0; kb < 8; ++kb) {
      if (kb < 7) { loadX(kb + 1); loadW(wsrc, D_DIM, kb + 1); }
      compute(&Xs[0][0], 72, acc);
      __syncthreads();
      if (kb < 7) { writeX(); writeW(); __syncthreads(); }
    }
    #pragma unroll
    for (int ri = 0; ri < 4; ++ri)
      #pragma unroll
      for (int bi = 0; bi < 4; ++bi)
        #pragma unroll
        for (int j = 0; j < 4; ++j) {
          int r = ri * 16 + rquad + j;
          int c = wid * 64 + bi * 16 + rl;
          if (which == 0) {
            Act[r][c] = f2bf(acc[ri][bi][j]);
          } else {
            float hg = bf2f(Act[r][c]);
            float a = hg / (1.f + __expf(-hg)) * acc[ri][bi][j];
            Act[r][c] = f2bf(a);
          }
        }
    __syncthreads();
  }

  #pragma unroll 1
  for (int np = 0; np < 2; ++np) {
    const float* wsrc = wd_ + ((size_t)e * D_DIM + np * 256) * F_DIM;
    f32x4 acc[4][4];
    #pragma unroll
    for (int ri = 0; ri < 4; ++ri)
      #pragma unroll
      for (int bi = 0; bi < 4; ++bi) acc[ri][bi] = fzero;

    loadW(wsrc, F_DIM, 0); writeW();
    __syncthreads();
    for (int kb = 0; kb < 4; ++kb) {
      if (kb < 3) loadW(wsrc, F_DIM, kb + 1);
      compute(&Act[0][kb * 64], 264, acc);
      __syncthreads();
      if (kb < 3) { writeW(); __syncthreads(); }
    }
    #pragma unroll
    for (int ri = 0; ri < 4; ++ri)
      #pragma unroll
      for (int bi = 0; bi < 4; ++bi)
        #pragma unroll
        for (int j = 0; j < 4; ++j) {
          int r = ri * 16 + rquad + j;
          int t = toks[r];
          if (t >= 0) {
            int c = np * 256 + wid * 64 + bi * 16 + rl;
            atomicAdd(out + (size_t)t * D_DIM + c, gts[r] * acc[ri][bi][j]);
          }
        }
  }
}

__global__ void __launch_bounds__(256, 2) shared_ffn_mfma(
    const float* __restrict__ x, const float* __restrict__ swg,
    const float* __restrict__ swu, const float* __restrict__ swd,
    float* __restrict__ out) {
  const int row0 = blockIdx.x * 32;

  __shared__ ushort Xs[32][72];
  __shared__ ushort Ws[256][72];
  __shared__ ushort Act[32][264];

  const int tid = threadIdx.x;
  const int lane = tid & 63;
  const int wid = tid >> 6;
  const int rl = lane & 15;
  const int ko = (lane >> 4) * 8;
  const int rquad = (lane >> 4) * 4;

  float4 px[2], pw[16];

  auto loadX = [&](int kb) {
    #pragma unroll
    for (int it = 0; it < 2; ++it) {
      int idx = tid + it * 256;
      int row = idx >> 4, c4 = (idx & 15) << 2;
      px[it] = *(const float4*)(x + (size_t)(row0 + row) * D_DIM + kb * 64 + c4);
    }
  };
  auto writeX = [&]() {
    #pragma unroll
    for (int it = 0; it < 2; ++it) {
      int idx = tid + it * 256;
      int row = idx >> 4, c4 = (idx & 15) << 2;
      ushort4 h; h.x = f2bf(px[it].x); h.y = f2bf(px[it].y);
      h.z = f2bf(px[it].z); h.w = f2bf(px[it].w);
      *(ushort4*)&Xs[row][c4] = h;
    }
  };
  auto loadW = [&](const float* src, int ldk, int kb) {
    #pragma unroll
    for (int it = 0; it < 16; ++it) {
      int idx = tid + it * 256;
      int row = idx >> 4, c4 = (idx & 15) << 2;
      pw[it] = *(const float4*)(src + (size_t)row * ldk + kb * 64 + c4);
    }
  };
  auto writeW = [&]() {
    #pragma unroll
    for (int it = 0; it < 16; ++it) {
      int idx = tid + it * 256;
      int row = idx >> 4, c4 = (idx & 15) << 2;
      ushort4 h; h.x = f2bf(pw[it].x); h.y = f2bf(pw[it].y);
      h.z = f2bf(pw[it].z); h.w = f2bf(pw[it].w);
      *(ushort4*)&Ws[row][c4] = h;
    }
  };
  auto compute = [&](const ushort* Ab, int lda, f32x4 (&acc)[2][4]) {
    #pragma unroll
    for (int kk = 0; kk < 2; ++kk) {
      bf16x8 a[2], b[4];
      #pragma unroll
      for (int ri = 0; ri < 2; ++ri)
        a[ri] = *(const bf16x8*)(Ab + (size_t)(ri * 16 + rl) * lda + kk * 32 + ko);
      #pragma unroll
      for (int bi = 0; bi < 4; ++bi)
        b[bi] = *(const bf16x8*)(&Ws[wid * 64 + bi * 16 + rl][kk * 32 + ko]);
      #pragma unroll
      for (int ri = 0; ri < 2; ++ri)
        #pragma unroll
        for (int bi = 0; bi < 4; ++bi)
          acc[ri][bi] = __builtin_amdgcn_mfma_f32_16x16x32_bf16(a[ri], b[bi], acc[ri][bi], 0, 0, 0);
    }
  };

  const f32x4 fzero = {0.f, 0.f, 0.f, 0.f};
  f32x4 accd[2][2][4];
  #pragma unroll
  for (int np = 0; np < 2; ++np)
    #pragma unroll
    for (int ri = 0; ri < 2; ++ri)
      #pragma unroll
      for (int bi = 0; bi < 4; ++bi) accd[np][ri][bi] = fzero;

  #pragma unroll 1
  for (int sh = 0; sh < SH_NUM; ++sh) {
    #pragma unroll 1
    for (int which = 0; which < 2; ++which) {
      const float* wsrc = (which == 0 ? swg : swu) + (size_t)sh * F_DIM * D_DIM;
      f32x4 acc[2][4];
      #pragma unroll
      for (int ri = 0; ri < 2; ++ri)
        #pragma unroll
        for (int bi = 0; bi < 4; ++bi) acc[ri][bi] = fzero;

      loadX(0); loadW(wsrc, D_DIM, 0);
      writeX(); writeW();
      __syncthreads();
      for (int kb = 0; kb < 8; ++kb) {
        if (kb < 7) { loadX(kb + 1); loadW(wsrc, D_DIM, kb + 1); }
        compute(&Xs[0][0], 72, acc);
        __syncthreads();
        if (kb < 7) { writeX(); writeW(); __syncthreads(); }
      }
      #pragma unroll
      for (int ri = 0; ri < 2; ++ri)
        #pragma unroll
        for (int bi = 0; bi < 4; ++bi)
          #pragma unroll
          for (int j = 0; j < 4; ++j) {
            int r = ri * 16 + rquad + j;
            int c = wid * 64 + bi * 16 + rl;
            if (which == 0) {
              Act[r][c] = f2bf(acc[ri][bi][j]);
            } else {
              float hg = bf2f(Act[r][c]);
              float a = hg / (1.f + __expf(-hg)) * acc[ri][bi][j];
              Act[r][c] = f2bf(a);
            }
          }
      __syncthreads();
    }
    #pragma unroll
    for (int np = 0; np < 2; ++np) {
      const float* wsrc = swd + ((size_t)sh * D_DIM + np * 256) * F_DIM;
      loadW(wsrc, F_DIM, 0); writeW();
      __syncthreads();
      for (int kb = 0; kb < 4; ++kb) {
        if (kb < 3) loadW(wsrc, F_DIM, kb + 1);
        compute(&Act[0][kb * 64], 264, accd[np]);
        __syncthreads();
        if (kb < 3) { writeW(); __syncthreads(); }
      }
    }
  }

  #pragma unroll
  for (int np = 0; np < 2; ++np)
    #pragma unroll
    for (int ri = 0; ri < 2; ++ri)
      #pragma unroll
      for (int bi = 0; bi < 4; ++bi)
        #pragma unroll
        for (int j = 0; j < 4; ++j) {
          int r = ri * 16 + rquad + j;
          int c = np * 256 + wid * 64 + bi * 16 + rl;
          out[(size_t)(row0 + r) * D_DIM + c] = 0.5f * accd[np][ri][bi][j];
        }
}

extern "C" void kernel_launch(void* const* d_in, const int* in_sizes, int n_in,
                              void* d_out, int out_size, void* d_ws, size_t ws_size,
                              hipStream_t stream) {
  const float* x    = (const float*)d_in[0];
  const float* rw   = (const float*)d_in[1];
  const float* bias = (const float*)d_in[2];
  const float* swg  = (const float*)d_in[3];
  const float* swu  = (const float*)d_in[4];
  const float* swd  = (const float*)d_in[5];
  const float* wg   = (const float*)d_in[6];
  const float* wu   = (const float*)d_in[7];
  const float* wd   = (const float*)d_in[8];
  float* out = (float*)d_out;

  const size_t small = 2 * (size_t)M_ENT * 4 + (size_t)M_ENT * 4 +
                       2 * (size_t)NCHUNK * E_NUM * 4 + 2 * (size_t)TOK_TOTAL * 4 +
                       RWT_BYTES;
  const size_t need_mid = X_BF_BYTES + WT_BYTES + small;
  const size_t need_big = need_mid + EO_BYTES;

  if (ws_size >= need_mid) {
    const bool gather = (ws_size >= need_big);
    char* ws = (char*)d_ws;
    ushort* x_bf     = (ushort*)ws; ws += X_BF_BYTES;
    ushort* Wt       = (ushort*)ws; ws += WT_BYTES;
    int*   topk_i    = (int*)ws;    ws += (size_t)M_ENT * 4;
    float* topk_p    = (float*)ws;  ws += (size_t)M_ENT * 4;
    int*   entry_row = (int*)ws;    ws += (size_t)M_ENT * 4;
    int*   chunk_hist= (int*)ws;    ws += (size_t)NCHUNK * E_NUM * 4;
    int*   chunk_base= (int*)ws;    ws += (size_t)NCHUNK * E_NUM * 4;
    int*   tok_all   = (int*)ws;    ws += (size_t)TOK_TOTAL * 4;
    float* gate_all  = (float*)ws;  ws += (size_t)TOK_TOTAL * 4;
    float* rwt       = (float*)ws;  ws += RWT_BYTES;
    ushort* eo       = (ushort*)ws; // only valid if gather

    prep_all<<<3320, 256, 0, stream>>>(x, x_bf, rw, rwt, tok_all, gate_all,
                                       wg, wu, wd, swg, swu, swd, Wt);
    router_topk2<<<256, 256, 0, stream>>>(x, rwt, bias, topk_i, topk_p);
    if (!gather) hipMemsetAsync(out, 0, (size_t)out_size * 4, stream);
    hist_kernel<<<NCHUNK, 256, 0, stream>>>(topk_i, chunk_hist);
    scan_kernel<<<1, 64, 0, stream>>>(chunk_hist, chunk_base);
    dispatch_kernel<<<NCHUNK, 256, 0, stream>>>(topk_i, topk_p, chunk_base, tok_all,
                                                gate_all, entry_row);
    const int nblk = (CAP / 128) * E_NUM + 2 * (N_TOK / 128);   // 768 + 128 = 896 = 8*112
    if (gather) {
      ffn_mfma<true><<<nblk, 512, 0, stream>>>(x_bf, Wt, tok_all, gate_all, out, eo);
      gather_out<<<N_TOK / 4, 256, 0, stream>>>(eo, entry_row, topk_p, out);
    } else {
      ffn_mfma<false><<<nblk, 512, 0, stream>>>(x_bf, Wt, tok_all, gate_all, out, nullptr);
    }
  } else {
    char* ws = (char*)d_ws;
    int*   topk_i      = (int*)ws;   ws += (size_t)M_ENT * 4;
    float* topk_p      = (float*)ws; ws += (size_t)M_ENT * 4;
    int*   chunk_hist  = (int*)ws;   ws += (size_t)NCHUNK * E_NUM * 4;
    int*   chunk_base  = (int*)ws;   ws += (size_t)NCHUNK * E_NUM * 4;
    int*   expert_tok  = (int*)ws;   ws += (size_t)E_NUM * CAP * 4;
    float* expert_gate = (float*)ws; ws += (size_t)E_NUM * CAP * 4;

    router_topk<<<N_TOK / 4, 256, 0, stream>>>(x, rw, bias, topk_i, topk_p);
    hipMemsetAsync(expert_tok, 0xFF, (size_t)E_NUM * CAP * 4, stream);
    hist_kernel<<<NCHUNK, 256, 0, stream>>>(topk_i, chunk_hist);
    scan_kernel<<<1, 64, 0, stream>>>(chunk_hist, chunk_base);
    dispatch_kernel<<<NCHUNK, 256, 0, stream>>>(topk_i, topk_p, chunk_base, expert_tok,
                                                expert_gate, nullptr);
    shared_ffn_mfma<<<N_TOK / 32, 256, 0, stream>>>(x, swg, swu, swd, out);
    expert_ffn_mfma<<<(CAP / 64) * E_NUM, 256, 0, stream>>>(x, wg, wu, wd, expert_tok,
                                                            expert_gate, out);
  }
}

// Round 15
// 255.646 us; speedup vs baseline: 1.4813x; 1.0370x over previous
//
#include <hip/hip_runtime.h>
#include <hip/hip_bf16.h>
#include <math.h>

#define N_TOK 8192
#define D_DIM 512
#define F_DIM 256
#define E_NUM 64
#define SH_NUM 2
#define K_TOP 6
#define CAP   1536
#define M_ENT (N_TOK * K_TOP)   // 49152
#define NCHUNK (M_ENT / 256)    // 192

#define EW_STRIDE 393216            // shorts per expert blob (48 chunks x 8192)
#define E_TOT (E_NUM + SH_NUM)      // 66
#define X_BF_BYTES   (8388608ull)
#define WT_BYTES     ((size_t)E_TOT * EW_STRIDE * 2)
#define TOK_ROUTED   (E_NUM * CAP)                   // 98304
#define TOK_TOTAL    (TOK_ROUTED + SH_NUM * N_TOK)   // 114688
#define EO_BYTES     ((size_t)TOK_TOTAL * D_DIM * 2)
#define RWT_BYTES    131072ull

typedef __attribute__((ext_vector_type(8))) short bf16x8;
typedef __attribute__((ext_vector_type(8))) short short8;
typedef __attribute__((ext_vector_type(4))) float f32x4;

__device__ __forceinline__ ushort f2bf(float f) {
  union { float f; unsigned u; } c; c.f = f;
  return (ushort)((c.u + 0x7FFFu + ((c.u >> 16) & 1u)) >> 16);
}
__device__ __forceinline__ float bf2f(ushort h) {
  union { unsigned u; float f; } c; c.u = ((unsigned)h) << 16;
  return c.f;
}

// ---------------- legacy router (small-ws path) ----------------
__global__ void router_topk(const float* __restrict__ x, const float* __restrict__ rw,
                            const float* __restrict__ bias, int* __restrict__ topk_i,
                            float* __restrict__ topk_p) {
  const int wave = threadIdx.x >> 6;
  const int lane = threadIdx.x & 63;
  const int n = blockIdx.x * 4 + wave;
  if (n >= N_TOK) return;

  const float4* xr = (const float4*)(x + (size_t)n * D_DIM);
  const float4* wr = (const float4*)(rw + (size_t)lane * D_DIM);
  float acc = 0.f;
  #pragma unroll 4
  for (int d4 = 0; d4 < D_DIM / 4; ++d4) {
    float4 xv = xr[d4]; float4 wv = wr[d4];
    acc += xv.x * wv.x + xv.y * wv.y + xv.z * wv.z + xv.w * wv.w;
  }
  float logit = acc + bias[lane];

  float m = logit;
  for (int off = 32; off > 0; off >>= 1) m = fmaxf(m, __shfl_xor(m, off));
  float p = expf(logit - m);
  float s = p;
  for (int off = 32; off > 0; off >>= 1) s += __shfl_xor(s, off);
  float prob = p / s;

  float myp = prob;
  float gsum = 0.f;
  float myg = 0.f; int myi = -1;
  for (int k = 0; k < K_TOP; ++k) {
    float bp = myp; int bi = lane;
    for (int off = 32; off > 0; off >>= 1) {
      float op = __shfl_xor(bp, off); int oi = __shfl_xor(bi, off);
      if (op > bp || (op == bp && oi < bi)) { bp = op; bi = oi; }
    }
    gsum += bp;
    if (lane == k) { myg = bp; myi = bi; }
    if (lane == bi) myp = -1.f;
  }
  if (lane < K_TOP) {
    topk_i[n * K_TOP + lane] = myi;
    topk_p[n * K_TOP + lane] = myg / (gsum + 1e-9f);
  }
}

__device__ __forceinline__ void softmax_topk_write(float logit, int n, int lane,
                                                   int* __restrict__ topk_i,
                                                   float* __restrict__ topk_p) {
  float m = logit;
  for (int off = 32; off > 0; off >>= 1) m = fmaxf(m, __shfl_xor(m, off));
  float p = expf(logit - m);
  float s = p;
  for (int off = 32; off > 0; off >>= 1) s += __shfl_xor(s, off);
  float prob = p / s;

  float myp = prob;
  float gsum = 0.f;
  float myg = 0.f; int myi = -1;
  #pragma unroll 1
  for (int k = 0; k < K_TOP; ++k) {
    float bp = myp; int bi = lane;
    for (int off = 32; off > 0; off >>= 1) {
      float op = __shfl_xor(bp, off); int oi = __shfl_xor(bi, off);
      if (op > bp || (op == bp && oi < bi)) { bp = op; bi = oi; }
    }
    gsum += bp;
    if (lane == k) { myg = bp; myi = bi; }
    if (lane == bi) myp = -1.f;
  }
  if (lane < K_TOP) {
    topk_i[n * K_TOP + lane] = myi;
    topk_p[n * K_TOP + lane] = myg / (gsum + 1e-9f);
  }
}

__global__ void __launch_bounds__(256) router_topk2(
    const float* __restrict__ x, const float* __restrict__ rwt,
    const float* __restrict__ bias, int* __restrict__ topk_i,
    float* __restrict__ topk_p) {
  const int wave = threadIdx.x >> 6;
  const int lane = threadIdx.x & 63;
  const int n0 = blockIdx.x * 32 + wave * 8;

  float acc[8];
  #pragma unroll
  for (int t = 0; t < 8; ++t) acc[t] = 0.f;

  const float4* wv4 = (const float4*)rwt;
  #pragma unroll 2
  for (int k4 = 0; k4 < 128; ++k4) {
    float4 w = wv4[k4 * 64 + lane];
    #pragma unroll
    for (int t = 0; t < 8; ++t) {
      float4 xv = *(const float4*)(x + (size_t)(n0 + t) * D_DIM + k4 * 4);
      acc[t] += xv.x * w.x + xv.y * w.y + xv.z * w.z + xv.w * w.w;
    }
  }
  float b = bias[lane];
  #pragma unroll 1
  for (int t = 0; t < 8; ++t)
    softmax_topk_write(acc[t] + b, n0 + t, lane, topk_i, topk_p);
}

// ---------------- per-chunk expert histogram ----------------
__global__ void hist_kernel(const int* __restrict__ topk_i, int* __restrict__ chunk_hist) {
  __shared__ int h[E_NUM];
  const int tid = threadIdx.x;
  if (tid < E_NUM) h[tid] = 0;
  __syncthreads();
  int e = topk_i[blockIdx.x * 256 + tid];
  atomicAdd(&h[e], 1);
  __syncthreads();
  if (tid < E_NUM) chunk_hist[blockIdx.x * E_NUM + tid] = h[tid];
}

// ---------------- exclusive scan over chunks, per expert ----------------
__global__ void scan_kernel(const int* __restrict__ chunk_hist, int* __restrict__ chunk_base) {
  const int e = threadIdx.x;
  int run = 0;
  for (int c = 0; c < NCHUNK; ++c) {
    chunk_base[c * E_NUM + e] = run;
    run += chunk_hist[c * E_NUM + e];
  }
}

// ---------------- dispatch: slot = global stable rank within expert ----------------
__global__ void dispatch_kernel(const int* __restrict__ topk_i, const float* __restrict__ topk_p,
                                const int* __restrict__ chunk_base,
                                int* __restrict__ expert_tok, float* __restrict__ expert_gate,
                                int* __restrict__ entry_row) {
  __shared__ int eid[256];
  const int tid = threadIdx.x;
  const int m = blockIdx.x * 256 + tid;
  const int e = topk_i[m];
  eid[tid] = e;
  __syncthreads();
  int rank = 0;
  for (int t = 0; t < tid; ++t) rank += (eid[t] == e);
  int slot = chunk_base[blockIdx.x * E_NUM + e] + rank;
  int row = -1;
  if (slot < CAP) {
    expert_tok[e * CAP + slot] = m / K_TOP;
    expert_gate[e * CAP + slot] = topk_p[m];
    row = e * CAP + slot;
  }
  if (entry_row) entry_row[m] = row;
}

// ================= FAST PATH =================

// merged: x fp32->bf16 (blocks 0..2047), transpose_rw (2048..2079), init_shared (2080..2143)
__global__ void convert_x_misc(const float* __restrict__ x, ushort* __restrict__ xb,
                               const float* __restrict__ rw, float* __restrict__ rwt,
                               int* __restrict__ tok_all, float* __restrict__ gate_all) {
  int b = blockIdx.x;
  if (b < 2048) {
    size_t idx = (size_t)b * 256 + threadIdx.x;
    const float4* s4 = (const float4*)(x + idx * 8);
    float4 v0 = s4[0], v1 = s4[1];
    short8 o;
    o[0] = f2bf(v0.x); o[1] = f2bf(v0.y); o[2] = f2bf(v0.z); o[3] = f2bf(v0.w);
    o[4] = f2bf(v1.x); o[5] = f2bf(v1.y); o[6] = f2bf(v1.z); o[7] = f2bf(v1.w);
    *(short8*)(xb + idx * 8) = o;
  } else if (b < 2080) {
    int idx = (b - 2048) * 256 + threadIdx.x;   // 0..8191 exactly
    int e = idx >> 7, k4 = idx & 127;
    float4 v = *(const float4*)(rw + (size_t)e * D_DIM + k4 * 4);
    *(float4*)(rwt + ((size_t)k4 * 64 + e) * 4) = v;
  } else {
    int i = (b - 2080) * 256 + threadIdx.x;     // 0..16383 exactly
    tok_all[TOK_ROUTED + i] = i & (N_TOK - 1);
    gate_all[TOK_ROUTED + i] = 0.5f;
  }
}

// weights fp32 -> bf16, pre-tiled fragment layout; dest-linear writes.
__global__ void convert_w(const float* __restrict__ wg_, const float* __restrict__ wu_,
                          const float* __restrict__ wd_, const float* __restrict__ swg,
                          const float* __restrict__ swu, const float* __restrict__ swd,
                          ushort* __restrict__ Wt) {
  int e = blockIdx.x / 12;
  int rem = blockIdx.x - e * 12;
  int p = rem >> 2, q = rem & 3;
  const float* src;
  if (p == 0)      src = (e < E_NUM) ? wg_ + (size_t)e * 131072 : swg + (size_t)(e - E_NUM) * 131072;
  else if (p == 1) src = (e < E_NUM) ? wu_ + (size_t)e * 131072 : swu + (size_t)(e - E_NUM) * 131072;
  else             src = (e < E_NUM) ? wd_ + (size_t)e * 131072 : swd + (size_t)(e - E_NUM) * 131072;
  ushort* dst = Wt + (size_t)e * EW_STRIDE + (size_t)p * 131072;
  #pragma unroll
  for (int i = 0; i < 16; ++i) {
    int d = q * 32768 + i * 2048 + threadIdx.x * 8;
    int ci = d >> 13;
    int r  = d & 8191;
    int nt = r >> 9;
    int rr = r & 511;
    int k8 = rr >> 7;
    int n  = nt * 16 + ((rr >> 3) & 15);
    size_t srcidx;
    if (p < 2) {
      srcidx = (size_t)n * 512 + ci * 32 + k8 * 8;
    } else {
      int np = ci >> 3, kc = ci & 7;
      srcidx = (size_t)(np * 256 + n) * 256 + kc * 32 + k8 * 8;
    }
    const float4* s4 = (const float4*)(src + srcidx);
    float4 v0 = s4[0], v1 = s4[1];
    short8 o;
    o[0] = f2bf(v0.x); o[1] = f2bf(v0.y); o[2] = f2bf(v0.z); o[3] = f2bf(v0.w);
    o[4] = f2bf(v1.x); o[5] = f2bf(v1.y); o[6] = f2bf(v1.z); o[7] = f2bf(v1.w);
    *(short8*)(dst + d) = o;
  }
}

// Unified FFN v5: 128-token tile, 512 threads (8 waves, 2r x 4c).
// ALL operands (W and X) loaded GLOBAL->REG; no LDS and NO barriers in the
// gate+up loop. Only 2 __syncthreads in the kernel (toks load, Act ready).
// XCD-aware decode; grid MUST be 896 = 8 * 112.
template <bool GATHER>
__global__ void __launch_bounds__(512, 1) ffn_mfma(
    const ushort* __restrict__ xb, const ushort* __restrict__ Wt,
    const int* __restrict__ tok_all, const float* __restrict__ gate_all,
    float* __restrict__ out, ushort* __restrict__ expert_out) {
  int e, tbase;
  {
    int xcd = blockIdx.x & 7;
    int j = blockIdx.x >> 3;          // 0..111
    if (j < 96) {                     // routed: 8 experts x 12 tiles per class
      int ec = j / 12;
      int mt = j - ec * 12;
      e = ec * 8 + xcd;
      tbase = e * CAP + mt * 128;
      if (tok_all[tbase] < 0) return;
    } else {                          // shared: 16 tiles per class (128 total)
      int s = xcd * 16 + (j - 96);
      int sh = s & 1, mt = s >> 1;
      e = E_NUM + sh;
      tbase = TOK_ROUTED + sh * N_TOK + mt * 128;
    }
  }
  const ushort* wbase = Wt + (size_t)e * EW_STRIDE;

  __shared__ ushort Act[32768];       // 64 KB
  __shared__ int   toks[128];
  __shared__ float gts[128];

  const int tid = threadIdx.x;
  const int lane = tid & 63;
  const int wid = tid >> 6;        // 0..7
  const int wr = wid >> 2;         // 0..1
  const int wc = wid & 3;          // 0..3
  const int rl = lane & 15;
  const int hi = lane >> 4;

  if (tid < 128) {
    int t = tok_all[tbase + tid];
    toks[tid] = t;
    gts[tid] = (t >= 0) ? gate_all[tbase + tid] : 0.f;
  }
  __syncthreads();

  // per-lane X row pointers: A-fragment row = wr*64 + ri*16 + (lane&15)
  const ushort* xA[4];
  #pragma unroll
  for (int ri = 0; ri < 4; ++ri) {
    int t = toks[wr * 64 + ri * 16 + rl];
    xA[ri] = xb + (size_t)(t < 0 ? 0 : t) * D_DIM + hi * 8;
  }

  auto loadXr = [&](int kc, bf16x8 (&a)[4]) {
    #pragma unroll
    for (int ri = 0; ri < 4; ++ri)
      a[ri] = *(const bf16x8*)(xA[ri] + kc * 32);
  };
  auto loadW = [&](int kc, bf16x8 (&g)[4], bf16x8 (&u)[4]) {
    #pragma unroll
    for (int bi = 0; bi < 4; ++bi) {
      const ushort* p = wbase + kc * 8192 + (wc * 4 + bi) * 512 + lane * 8;
      g[bi] = *(const bf16x8*)p;
      u[bi] = *(const bf16x8*)(p + 131072);
    }
  };

  const f32x4 fzero = {0.f, 0.f, 0.f, 0.f};
  f32x4 accg[4][4], accu[4][4];
  #pragma unroll
  for (int ri = 0; ri < 4; ++ri)
    #pragma unroll
    for (int bi = 0; bi < 4; ++bi) { accg[ri][bi] = fzero; accu[ri][bi] = fzero; }

  auto guMFMA = [&](bf16x8 (&a)[4], bf16x8 (&g)[4], bf16x8 (&u)[4]) {
    __builtin_amdgcn_s_setprio(1);
    #pragma unroll
    for (int bi = 0; bi < 4; ++bi)
      #pragma unroll
      for (int ri = 0; ri < 4; ++ri) {
        accg[ri][bi] = __builtin_amdgcn_mfma_f32_16x16x32_bf16(a[ri], g[bi], accg[ri][bi], 0, 0, 0);
        accu[ri][bi] = __builtin_amdgcn_mfma_f32_16x16x32_bf16(a[ri], u[bi], accu[ri][bi], 0, 0, 0);
      }
    __builtin_amdgcn_s_setprio(0);
  };

  // ---- fused gate+up: 16 K-steps of 32; barrier-free reg pipeline ----
  {
    bf16x8 gA[4], uA[4], gB[4], uB[4], aA[4], aB[4];
    loadW(0, gA, uA); loadXr(0, aA);
    #pragma unroll 1
    for (int k2 = 0; k2 < 16; k2 += 2) {
      loadW(k2 + 1, gB, uB); loadXr(k2 + 1, aB);
      guMFMA(aA, gA, uA);
      if (k2 + 2 < 16) { loadW(k2 + 2, gA, uA); loadXr(k2 + 2, aA); }
      guMFMA(aB, gB, uB);
    }
  }

  // ---- silu(g)*u in-register -> Act (fragment-tiled bf16) ----
  #pragma unroll
  for (int ri = 0; ri < 4; ++ri)
    #pragma unroll
    for (int bi = 0; bi < 4; ++bi) {
      int st = (wr * 4 + ri) * 8 + wc * 2 + (bi >> 1);
      int base = st * 512 + ((bi & 1) * 2 + (rl >> 3)) * 128 + (rl & 7);
      #pragma unroll
      for (int j = 0; j < 4; ++j) {
        float g = accg[ri][bi][j], u = accu[ri][bi][j];
        Act[base + (hi * 4 + j) * 8] = f2bf(g / (1.f + __expf(-g)) * u);
      }
    }

  // ---- down: out[128 x 512], 8 K-steps of 32 over F; barrier-free ----
  const ushort* wdbase = wbase + 262144 + (wc >> 1) * 65536 + ((wc & 1) * 8) * 512 + lane * 8;
  auto loadWd = [&](int kc, bf16x8 (&d)[8]) {
    #pragma unroll
    for (int bj = 0; bj < 8; ++bj)
      d[bj] = *(const bf16x8*)(wdbase + kc * 8192 + bj * 512);
  };

  f32x4 accd[4][8];
  #pragma unroll
  for (int ri = 0; ri < 4; ++ri)
    #pragma unroll
    for (int bj = 0; bj < 8; ++bj) accd[ri][bj] = fzero;

  bf16x8 dA[8], dB[8];
  loadWd(0, dA);
  __syncthreads();   // Act ready

  auto dnMFMA = [&](int kc, bf16x8 (&d)[8]) {
    bf16x8 a[4];
    #pragma unroll
    for (int ri = 0; ri < 4; ++ri)
      a[ri] = *(const bf16x8*)(&Act[((wr * 4 + ri) * 8 + kc) * 512 + lane * 8]);
    __builtin_amdgcn_s_setprio(1);
    #pragma unroll
    for (int bj = 0; bj < 8; ++bj)
      #pragma unroll
      for (int ri = 0; ri < 4; ++ri)
        accd[ri][bj] = __builtin_amdgcn_mfma_f32_16x16x32_bf16(a[ri], d[bj], accd[ri][bj], 0, 0, 0);
    __builtin_amdgcn_s_setprio(0);
  };

  #pragma unroll 1
  for (int k2 = 0; k2 < 8; k2 += 2) {
    loadWd(k2 + 1, dB);
    dnMFMA(k2, dA);
    if (k2 + 2 < 8) loadWd(k2 + 2, dA);
    dnMFMA(k2 + 1, dB);
  }

  // ---- epilogue ----
  if (GATHER) {
    #pragma unroll
    for (int ri = 0; ri < 4; ++ri)
      #pragma unroll
      for (int j = 0; j < 4; ++j) {
        int r = wr * 64 + ri * 16 + hi * 4 + j;
        if (toks[r] < 0) continue;
        ushort* erow = expert_out + (size_t)(tbase + r) * D_DIM + wc * 128 + rl;
        #pragma unroll
        for (int bj = 0; bj < 8; ++bj)
          erow[bj * 16] = f2bf(accd[ri][bj][j]);
      }
  } else {
    #pragma unroll
    for (int ri = 0; ri < 4; ++ri)
      #pragma unroll
      for (int j = 0; j < 4; ++j) {
        int r = wr * 64 + ri * 16 + hi * 4 + j;
        int t = toks[r];
        if (t < 0) continue;
        float gt = gts[r];
        float* orow = out + (size_t)t * D_DIM + wc * 128 + rl;
        #pragma unroll
        for (int bj = 0; bj < 8; ++bj)
          atomicAdd(orow + bj * 16, gt * accd[ri][bj][j]);
      }
  }
}

// ---------------- gather combine: one wave per token ----------------
__global__ void __launch_bounds__(256) gather_out(
    const ushort* __restrict__ eo, const int* __restrict__ entry_row,
    const float* __restrict__ topk_p, float* __restrict__ out) {
  const int t = blockIdx.x * 4 + (threadIdx.x >> 6);
  const int lane = threadIdx.x & 63;
  const int base = t * K_TOP;

  float acc[8];
  #pragma unroll
  for (int j = 0; j < 8; ++j) acc[j] = 0.f;

  #pragma unroll
  for (int k = 0; k < K_TOP; ++k) {
    int row = entry_row[base + k];
    if (row >= 0) {
      float g = topk_p[base + k];
      bf16x8 v = *(const bf16x8*)(eo + (size_t)row * D_DIM + lane * 8);
      #pragma unroll
      for (int j = 0; j < 8; ++j) acc[j] += g * bf2f((ushort)v[j]);
    }
  }
  #pragma unroll
  for (int sh = 0; sh < SH_NUM; ++sh) {
    int row = TOK_ROUTED + sh * N_TOK + t;
    bf16x8 v = *(const bf16x8*)(eo + (size_t)row * D_DIM + lane * 8);
    #pragma unroll
    for (int j = 0; j < 8; ++j) acc[j] += 0.5f * bf2f((ushort)v[j]);
  }
  float4* o = (float4*)(out + (size_t)t * D_DIM + lane * 8);
  o[0] = make_float4(acc[0], acc[1], acc[2], acc[3]);
  o[1] = make_float4(acc[4], acc[5], acc[6], acc[7]);
}

// ================= LEGACY PATH (round-2, used when ws tiny) =================

__global__ void __launch_bounds__(256, 2) expert_ffn_mfma(
    const float* __restrict__ x, const float* __restrict__ wg_,
    const float* __restrict__ wu_, const float* __restrict__ wd_,
    const int* __restrict__ expert_tok, const float* __restrict__ expert_gate,
    float* __restrict__ out) {
  const int e = blockIdx.x & (E_NUM - 1);
  const int mt = blockIdx.x >> 6;
  const int s0 = mt * 64;
  if (expert_tok[e * CAP + s0] < 0) return;

  __shared__ ushort Xs[64][72];
  __shared__ ushort Ws[256][72];
  __shared__ ushort Act[64][264];
  __shared__ int   toks[64];
  __shared__ float gts[64];

  const int tid = threadIdx.x;
  const int lane = tid & 63;
  const int wid = tid >> 6;
  const int rl = lane & 15;
  const int ko = (lane >> 4) * 8;
  const int rquad = (lane >> 4) * 4;

  if (tid < 64) {
    int t = expert_tok[e * CAP + s0 + tid];
    toks[tid] = t;
    gts[tid] = (t >= 0) ? expert_gate[e * CAP + s0 + tid] : 0.f;
  }
  __syncthreads();

  float4 px[4], pw[16];

  auto loadX = [&](int kb) {
    #pragma unroll
    for (int it = 0; it < 4; ++it) {
      int idx = tid + it * 256;
      int row = idx >> 4, c4 = (idx & 15) << 2;
      int t = toks[row];
      px[it] = (t >= 0) ? *(const float4*)(x + (size_t)t * D_DIM + kb * 64 + c4)
                        : make_float4(0.f, 0.f, 0.f, 0.f);
    }
  };
  auto writeX = [&]() {
    #pragma unroll
    for (int it = 0; it < 4; ++it) {
      int idx = tid + it * 256;
      int row = idx >> 4, c4 = (idx & 15) << 2;
      ushort4 h; h.x = f2bf(px[it].x); h.y = f2bf(px[it].y);
      h.z = f2bf(px[it].z); h.w = f2bf(px[it].w);
      *(ushort4*)&Xs[row][c4] = h;
    }
  };
  auto loadW = [&](const float* src, int ldk, int kb) {
    #pragma unroll
    for (int it = 0; it < 16; ++it) {
      int idx = tid + it * 256;
      int row = idx >> 4, c4 = (idx & 15) << 2;
      pw[it] = *(const float4*)(src + (size_t)row * ldk + kb * 64 + c4);
    }
  };
  auto writeW = [&]() {
    #pragma unroll
    for (int it = 0; it < 16; ++it) {
      int idx = tid + it * 256;
      int row = idx >> 4, c4 = (idx & 15) << 2;
      ushort4 h; h.x = f2bf(pw[it].x); h.y = f2bf(pw[it].y);
      h.z = f2bf(pw[it].z); h.w = f2bf(pw[it].w);
      *(ushort4*)&Ws[row][c4] = h;
    }
  };
  auto compute = [&](const ushort* Ab, int lda, f32x4 (&acc)[4][4]) {
    #pragma unroll
    for (int kk = 0; kk < 2; ++kk) {
      bf16x8 a[4], b[4];
      #pragma unroll
      for (int ri = 0; ri < 4; ++ri)
        a[ri] = *(const bf16x8*)(Ab + (size_t)(ri * 16 + rl) * lda + kk * 32 + ko);
      #pragma unroll
      for (int bi = 0; bi < 4; ++bi)
        b[bi] = *(const bf16x8*)(&Ws[wid * 64 + bi * 16 + rl][kk * 32 + ko]);
      #pragma unroll
      for (int ri = 0; ri < 4; ++ri)
        #pragma unroll
        for (int bi = 0; bi < 4; ++bi)
          acc[ri][bi] = __builtin_amdgcn_mfma_f32_16x16x32_bf16(a[ri], b[bi], acc[ri][bi], 0, 0, 0);
    }
  };

  const f32x4 fzero = {0.f, 0.f, 0.f, 0.f};

  #pragma unroll 1
  for (int which = 0; which < 2; ++which) {
    const float* wsrc = (which == 0 ? wg_ : wu_) + (size_t)e * F_DIM * D_DIM;
    f32x4 acc[4][4];
    #pragma unroll
    for (int ri = 0; ri < 4; ++ri)
      #pragma unroll
      for (int bi = 0; bi < 4; ++bi) acc[ri][bi] = fzero;

    loadX(0); loadW(wsrc, D_DIM, 0);
    writeX(); writeW();
    __syncthreads();
    for (int kb = 0; kb < 8; ++kb) {
      if (kb < 7) { loadX(kb + 1); loadW(wsrc, D_DIM, kb + 1); }
      compute(&Xs[0][0], 72, acc);
      __syncthreads();
      if (kb < 7) { writeX(); writeW(); __syncthreads(); }
    }
    #pragma unroll
    for (int ri = 0; ri < 4; ++ri)
      #pragma unroll
      for (int bi = 0; bi < 4; ++bi)
        #pragma unroll
        for (int j = 0; j < 4; ++j) {
          int r = ri * 16 + rquad + j;
          int c = wid * 64 + bi * 16 + rl;
          if (which == 0) {
            Act[r][c] = f2bf(acc[ri][bi][j]);
          } else {
            float hg = bf2f(Act[r][c]);
            float a = hg / (1.f + __expf(-hg)) * acc[ri][bi][j];
            Act[r][c] = f2bf(a);
          }
        }
    __syncthreads();
  }

  #pragma unroll 1
  for (int np = 0; np < 2; ++np) {
    const float* wsrc = wd_ + ((size_t)e * D_DIM + np * 256) * F_DIM;
    f32x4 acc[4][4];
    #pragma unroll
    for (int ri = 0; ri < 4; ++ri)
      #pragma unroll
      for (int bi = 0; bi < 4; ++bi) acc[ri][bi] = fzero;

    loadW(wsrc, F_DIM, 0); writeW();
    __syncthreads();
    for (int kb = 0; kb < 4; ++kb) {
      if (kb < 3) loadW(wsrc, F_DIM, kb + 1);
      compute(&Act[0][kb * 64], 264, acc);
      __syncthreads();
      if (kb < 3) { writeW(); __syncthreads(); }
    }
    #pragma unroll
    for (int ri = 0; ri < 4; ++ri)
      #pragma unroll
      for (int bi = 0; bi < 4; ++bi)
        #pragma unroll
        for (int j = 0; j < 4; ++j) {
          int r = ri * 16 + rquad + j;
          int t = toks[r];
          if (t >= 0) {
            int c = np * 256 + wid * 64 + bi * 16 + rl;
            atomicAdd(out + (size_t)t * D_DIM + c, gts[r] * acc[ri][bi][j]);
          }
        }
  }
}

__global__ void __launch_bounds__(256, 2) shared_ffn_mfma(
    const float* __restrict__ x, const float* __restrict__ swg,
    const float* __restrict__ swu, const float* __restrict__ swd,
    float* __restrict__ out) {
  const int row0 = blockIdx.x * 32;

  __shared__ ushort Xs[32][72];
  __shared__ ushort Ws[256][72];
  __shared__ ushort Act[32][264];

  const int tid = threadIdx.x;
  const int lane = tid & 63;
  const int wid = tid >> 6;
  const int rl = lane & 15;
  const int ko = (lane >> 4) * 8;
  const int rquad = (lane >> 4) * 4;

  float4 px[2], pw[16];

  auto loadX = [&](int kb) {
    #pragma unroll
    for (int it = 0; it < 2; ++it) {
      int idx = tid + it * 256;
      int row = idx >> 4, c4 = (idx & 15) << 2;
      px[it] = *(const float4*)(x + (size_t)(row0 + row) * D_DIM + kb * 64 + c4);
    }
  };
  auto writeX = [&]() {
    #pragma unroll
    for (int it = 0; it < 2; ++it) {
      int idx = tid + it * 256;
      int row = idx >> 4, c4 = (idx & 15) << 2;
      ushort4 h; h.x = f2bf(px[it].x); h.y = f2bf(px[it].y);
      h.z = f2bf(px[it].z); h.w = f2bf(px[it].w);
      *(ushort4*)&Xs[row][c4] = h;
    }
  };
  auto loadW = [&](const float* src, int ldk, int kb) {
    #pragma unroll
    for (int it = 0; it < 16; ++it) {
      int idx = tid + it * 256;
      int row = idx >> 4, c4 = (idx & 15) << 2;
      pw[it] = *(const float4*)(src + (size_t)row * ldk + kb * 64 + c4);
    }
  };
  auto writeW = [&]() {
    #pragma unroll
    for (int it = 0; it < 16; ++it) {
      int idx = tid + it * 256;
      int row = idx >> 4, c4 = (idx & 15) << 2;
      ushort4 h; h.x = f2bf(pw[it].x); h.y = f2bf(pw[it].y);
      h.z = f2bf(pw[it].z); h.w = f2bf(pw[it].w);
      *(ushort4*)&Ws[row][c4] = h;
    }
  };
  auto compute = [&](const ushort* Ab, int lda, f32x4 (&acc)[2][4]) {
    #pragma unroll
    for (int kk = 0; kk < 2; ++kk) {
      bf16x8 a[2], b[4];
      #pragma unroll
      for (int ri = 0; ri < 2; ++ri)
        a[ri] = *(const bf16x8*)(Ab + (size_t)(ri * 16 + rl) * lda + kk * 32 + ko);
      #pragma unroll
      for (int bi = 0; bi < 4; ++bi)
        b[bi] = *(const bf16x8*)(&Ws[wid * 64 + bi * 16 + rl][kk * 32 + ko]);
      #pragma unroll
      for (int ri = 0; ri < 2; ++ri)
        #pragma unroll
        for (int bi = 0; bi < 4; ++bi)
          acc[ri][bi] = __builtin_amdgcn_mfma_f32_16x16x32_bf16(a[ri], b[bi], acc[ri][bi], 0, 0, 0);
    }
  };

  const f32x4 fzero = {0.f, 0.f, 0.f, 0.f};
  f32x4 accd[2][2][4];
  #pragma unroll
  for (int np = 0; np < 2; ++np)
    #pragma unroll
    for (int ri = 0; ri < 2; ++ri)
      #pragma unroll
      for (int bi = 0; bi < 4; ++bi) accd[np][ri][bi] = fzero;

  #pragma unroll 1
  for (int sh = 0; sh < SH_NUM; ++sh) {
    #pragma unroll 1
    for (int which = 0; which < 2; ++which) {
      const float* wsrc = (which == 0 ? swg : swu) + (size_t)sh * F_DIM * D_DIM;
      f32x4 acc[2][4];
      #pragma unroll
      for (int ri = 0; ri < 2; ++ri)
        #pragma unroll
        for (int bi = 0; bi < 4; ++bi) acc[ri][bi] = fzero;

      loadX(0); loadW(wsrc, D_DIM, 0);
      writeX(); writeW();
      __syncthreads();
      for (int kb = 0; kb < 8; ++kb) {
        if (kb < 7) { loadX(kb + 1); loadW(wsrc, D_DIM, kb + 1); }
        compute(&Xs[0][0], 72, acc);
        __syncthreads();
        if (kb < 7) { writeX(); writeW(); __syncthreads(); }
      }
      #pragma unroll
      for (int ri = 0; ri < 2; ++ri)
        #pragma unroll
        for (int bi = 0; bi < 4; ++bi)
          #pragma unroll
          for (int j = 0; j < 4; ++j) {
            int r = ri * 16 + rquad + j;
            int c = wid * 64 + bi * 16 + rl;
            if (which == 0) {
              Act[r][c] = f2bf(acc[ri][bi][j]);
            } else {
              float hg = bf2f(Act[r][c]);
              float a = hg / (1.f + __expf(-hg)) * acc[ri][bi][j];
              Act[r][c] = f2bf(a);
            }
          }
      __syncthreads();
    }
    #pragma unroll
    for (int np = 0; np < 2; ++np) {
      const float* wsrc = swd + ((size_t)sh * D_DIM + np * 256) * F_DIM;
      loadW(wsrc, F_DIM, 0); writeW();
      __syncthreads();
      for (int kb = 0; kb < 4; ++kb) {
        if (kb < 3) loadW(wsrc, F_DIM, kb + 1);
        compute(&Act[0][kb * 64], 264, accd[np]);
        __syncthreads();
        if (kb < 3) { writeW(); __syncthreads(); }
      }
    }
  }

  #pragma unroll
  for (int np = 0; np < 2; ++np)
    #pragma unroll
    for (int ri = 0; ri < 2; ++ri)
      #pragma unroll
      for (int bi = 0; bi < 4; ++bi)
        #pragma unroll
        for (int j = 0; j < 4; ++j) {
          int r = ri * 16 + rquad + j;
          int c = np * 256 + wid * 64 + bi * 16 + rl;
          out[(size_t)(row0 + r) * D_DIM + c] = 0.5f * accd[np][ri][bi][j];
        }
}

extern "C" void kernel_launch(void* const* d_in, const int* in_sizes, int n_in,
                              void* d_out, int out_size, void* d_ws, size_t ws_size,
                              hipStream_t stream) {
  const float* x    = (const float*)d_in[0];
  const float* rw   = (const float*)d_in[1];
  const float* bias = (const float*)d_in[2];
  const float* swg  = (const float*)d_in[3];
  const float* swu  = (const float*)d_in[4];
  const float* swd  = (const float*)d_in[5];
  const float* wg   = (const float*)d_in[6];
  const float* wu   = (const float*)d_in[7];
  const float* wd   = (const float*)d_in[8];
  float* out = (float*)d_out;

  const size_t small = 2 * (size_t)M_ENT * 4 + (size_t)M_ENT * 4 +
                       2 * (size_t)NCHUNK * E_NUM * 4 + 2 * (size_t)TOK_TOTAL * 4 +
                       RWT_BYTES;
  const size_t need_mid = X_BF_BYTES + WT_BYTES + small;
  const size_t need_big = need_mid + EO_BYTES;

  if (ws_size >= need_mid) {
    const bool gather = (ws_size >= need_big);
    char* ws = (char*)d_ws;
    ushort* x_bf     = (ushort*)ws; ws += X_BF_BYTES;
    ushort* Wt       = (ushort*)ws; ws += WT_BYTES;
    int*   topk_i    = (int*)ws;    ws += (size_t)M_ENT * 4;
    float* topk_p    = (float*)ws;  ws += (size_t)M_ENT * 4;
    int*   entry_row = (int*)ws;    ws += (size_t)M_ENT * 4;
    int*   chunk_hist= (int*)ws;    ws += (size_t)NCHUNK * E_NUM * 4;
    int*   chunk_base= (int*)ws;    ws += (size_t)NCHUNK * E_NUM * 4;
    int*   tok_all   = (int*)ws;    ws += (size_t)TOK_TOTAL * 4;
    float* gate_all  = (float*)ws;  ws += (size_t)TOK_TOTAL * 4;
    float* rwt       = (float*)ws;  ws += RWT_BYTES;
    ushort* eo       = (ushort*)ws; // only valid if gather

    convert_x_misc<<<2144, 256, 0, stream>>>(x, x_bf, rw, rwt, tok_all, gate_all);
    convert_w<<<E_TOT * 12, 256, 0, stream>>>(wg, wu, wd, swg, swu, swd, Wt);
    router_topk2<<<256, 256, 0, stream>>>(x, rwt, bias, topk_i, topk_p);
    hipMemsetAsync(tok_all, 0xFF, (size_t)TOK_ROUTED * 4, stream);
    if (!gather) hipMemsetAsync(out, 0, (size_t)out_size * 4, stream);
    hist_kernel<<<NCHUNK, 256, 0, stream>>>(topk_i, chunk_hist);
    scan_kernel<<<1, 64, 0, stream>>>(chunk_hist, chunk_base);
    dispatch_kernel<<<NCHUNK, 256, 0, stream>>>(topk_i, topk_p, chunk_base, tok_all,
                                                gate_all, entry_row);
    const int nblk = (CAP / 128) * E_NUM + 2 * (N_TOK / 128);   // 768 + 128 = 896 = 8*112
    if (gather) {
      ffn_mfma<true><<<nblk, 512, 0, stream>>>(x_bf, Wt, tok_all, gate_all, out, eo);
      gather_out<<<N_TOK / 4, 256, 0, stream>>>(eo, entry_row, topk_p, out);
    } else {
      ffn_mfma<false><<<nblk, 512, 0, stream>>>(x_bf, Wt, tok_all, gate_all, out, nullptr);
    }
  } else {
    char* ws = (char*)d_ws;
    int*   topk_i      = (int*)ws;   ws += (size_t)M_ENT * 4;
    float* topk_p      = (float*)ws; ws += (size_t)M_ENT * 4;
    int*   chunk_hist  = (int*)ws;   ws += (size_t)NCHUNK * E_NUM * 4;
    int*   chunk_base  = (int*)ws;   ws += (size_t)NCHUNK * E_NUM * 4;
    int*   expert_tok  = (int*)ws;   ws += (size_t)E_NUM * CAP * 4;
    float* expert_gate = (float*)ws; ws += (size_t)E_NUM * CAP * 4;

    router_topk<<<N_TOK / 4, 256, 0, stream>>>(x, rw, bias, topk_i, topk_p);
    hipMemsetAsync(expert_tok, 0xFF, (size_t)E_NUM * CAP * 4, stream);
    hist_kernel<<<NCHUNK, 256, 0, stream>>>(topk_i, chunk_hist);
    scan_kernel<<<1, 64, 0, stream>>>(chunk_hist, chunk_base);
    dispatch_kernel<<<NCHUNK, 256, 0, stream>>>(topk_i, topk_p, chunk_base, expert_tok,
                                                expert_gate, nullptr);
    shared_ffn_mfma<<<N_TOK / 32, 256, 0, stream>>>(x, swg, swu, swd, out);
    expert_ffn_mfma<<<(CAP / 64) * E_NUM, 256, 0, stream>>>(x, wg, wu, wd, expert_tok,
                                                            expert_gate, out);
  }
}